// Round 9
// baseline (349.145 us; speedup 1.0000x reference)
//
#include <hip/hip_runtime.h>
#include <math.h>

// Problem constants (match reference)
#define S     512
#define Bsz   8
#define NCELL (S*S)              // 262144 = 2^18
#define NTOT  (Bsz*NCELL)        // 2097152
#define NFACE ((S-1)*S)          // 261632
#define CG_ITERS 20
#define NBLK3 512                // persistent grid: 64 blocks/batch, 8 rows/block
#define TS    16                 // k_setup tile

__device__ __constant__ float kINVH  = 511.0f;     // 1/h
__device__ __constant__ float kINV2H = 255.5f;
__device__ __constant__ float kH2    = (float)((1.0/511.0)*(1.0/511.0));

// ---------------- geometry (replicates numpy grid_helpers bit-exactly in double) ----
__device__ __forceinline__ void geom(int i, int j, float& rhob, float& bnx, float& bny) {
    double gx = (i == S-1) ? 1.0 : (double)i * (1.0/511.0);
    double gy = (j == S-1) ? 1.0 : (double)j * (1.0/511.0);
    double v0 = gx, v1 = 1.0 - gx, v2 = gy, v3 = 1.0 - gy;
    double m = v0; int am = 0;
    if (v1 < m) { m = v1; am = 1; }   // strict '<' == np.argmin first-min-wins
    if (v2 < m) { m = v2; am = 2; }
    if (v3 < m) { m = v3; am = 3; }
    float d = (float)m;
    rhob = expf(-(d*d) / 0.0225f);
    bnx = (am == 0) ? -1.f : (am == 1) ? 1.f : 0.f;
    bny = (am == 2) ? -1.f : (am == 3) ? 1.f : 0.f;
}

// ========== K_GEOM: batch-independent rb/bnx/bny planes (runs once, ~3 us) =========
// Removes ALL double-precision math from k_setup's hot path; stored floats are
// bit-identical to what geom() returned inline.
__global__ __launch_bounds__(256) void k_geom(float* __restrict__ rbT,
                                              float* __restrict__ bnxT,
                                              float* __restrict__ bnyT) {
    int t = blockIdx.x * 256 + threadIdx.x;    // 1024 blocks x 256 = 262144
    int i = t >> 9, j = t & 511;
    float rb, nx, ny;
    geom(i, j, rb, nx, ny);
    rbT[t] = rb; bnxT[t] = nx; bnyT[t] = ny;
}

// ---- per-cell fields; expressions identical to verified pipeline ------------------
__device__ __forceinline__ void cellfield8(const float* __restrict__ c,
                                           const float* __restrict__ uu,
                                           const float* __restrict__ bb,
                                           int i, int j, float* f) {
    int rem = i * S + j;
    float cc = c[rem];
    float uc = uu[rem];
    float lapv = 0.f;
    if (i > 0 && i < S-1 && j > 0 && j < S-1) {
        float un = uu[rem + S], us = uu[rem - S];
        float ue = uu[rem + 1], uw = uu[rem - 1];
        lapv = ((un - uc)*kINVH - (uc - us)*kINVH)*kINVH
             + ((ue - uc)*kINVH - (uc - uw)*kINVH)*kINVH;
    }
    float glx, gly;
    float lc = logf(fmaxf(cc, 1e-6f));
    if (i == 0)        { glx = (logf(fmaxf(c[rem+S],1e-6f)) - lc) * kINVH; }
    else if (i == S-1) { glx = (lc - logf(fmaxf(c[rem-S],1e-6f))) * kINVH; }
    else { glx = (logf(fmaxf(c[rem+S],1e-6f)) - logf(fmaxf(c[rem-S],1e-6f))) * kINV2H; }
    if (j == 0)        { gly = (logf(fmaxf(c[rem+1],1e-6f)) - lc) * kINVH; }
    else if (j == S-1) { gly = (lc - logf(fmaxf(c[rem-1],1e-6f))) * kINVH; }
    else { gly = (logf(fmaxf(c[rem+1],1e-6f)) - logf(fmaxf(c[rem-1],1e-6f))) * kINV2H; }
    float eta  = sqrtf(glx*glx + gly*gly + 1e-6f);
    float rhov = 1.f / (1.f + expf(-10.f * (eta - 0.5f)));
    float nhx = glx / eta, nhy = gly / eta;
    float4 b4 = ((const float4*)bb)[rem];
    f[0] = lapv; f[1] = rhov;
    f[2] = b4.y * nhx - b4.z * nhy;
    f[3] = b4.y * nhy + b4.z * nhx;
    f[4] = cc; f[5] = uc; f[6] = b4.x; f[7] = b4.w;
}

// ========== K_SETUP: geom() replaced by table reads (bit-identical values) =========
__global__ __launch_bounds__(256) void k_setup(
        const float* __restrict__ coeff, const float* __restrict__ u,
        const float* __restrict__ beta,
        const float* __restrict__ rbT, const float* __restrict__ bnxT,
        const float* __restrict__ bnyT,
        float* __restrict__ taux, float* __restrict__ tauyP,
        float* __restrict__ cxP, float* __restrict__ cyP) {
    __shared__ float sF[8][TS+1][TS+8];
    int b  = blockIdx.x >> 10;
    int tl = blockIdx.x & 1023;
    int i0 = (tl >> 5) << 4;
    int j0 = (tl & 31) << 4;
    int tx = threadIdx.x & 15, ty = threadIdx.x >> 4;
    const float* cB = coeff + (b << 18);
    const float* uB = u     + (b << 18);
    const float* bB = beta  + ((size_t)b << 20);

    {   float f[8];
        cellfield8(cB, uB, bB, i0 + ty, j0 + tx, f);
        #pragma unroll
        for (int q = 0; q < 8; ++q) sF[q][ty][tx] = f[q];
    }
    if (threadIdx.x < 16 && i0 + TS < S) {
        float f[8];
        cellfield8(cB, uB, bB, i0 + TS, j0 + threadIdx.x, f);
        #pragma unroll
        for (int q = 0; q < 8; ++q) sF[q][TS][threadIdx.x] = f[q];
    }
    if (threadIdx.x >= 64 && threadIdx.x < 80 && j0 + TS < S) {
        int k = threadIdx.x - 64;
        float f[8];
        cellfield8(cB, uB, bB, i0 + k, j0 + TS, f);
        #pragma unroll
        for (int q = 0; q < 8; ++q) sF[q][k][TS] = f[q];
    }
    __syncthreads();

    int ci = i0 + ty, cj = j0 + tx;
    int rem = ci * S + cj;
    float lap0 = sF[0][ty][tx], rho0 = sF[1][ty][tx];
    float sx0  = sF[2][ty][tx], sy0  = sF[3][ty][tx];
    float c0   = sF[4][ty][tx], u0   = sF[5][ty][tx];
    float bb0  = sF[6][ty][tx], bw0  = sF[7][ty][tx];
    float rb0 = rbT[rem], nx0 = bnxT[rem], ny0 = bnyT[rem];

    if (ci < S-1) {
        float lap1 = sF[0][ty+1][tx], rho1 = sF[1][ty+1][tx], sx1 = sF[2][ty+1][tx];
        float c1 = sF[4][ty+1][tx], u1 = sF[5][ty+1][tx];
        float bb1 = sF[6][ty+1][tx], bw1 = sF[7][ty+1][tx];
        float cx = 2.f * c1 * c0 / (c1 + c0 + 1e-6f);
        cxP[(b << 18) + rem] = cx;
        float t = 0.f;
        if (cj > 0 && cj < S-1) {
            float gux = (u1 - u0) * kINVH;
            float lgx = (lap1 - lap0) * kINVH;
            float rb1 = rbT[rem + S], nx1 = bnxT[rem + S];
            float abb  = 0.5f * (bb1 + bb0);
            float arho = 0.5f * (rho1 + rho0);
            float asx  = 0.5f * (sx1 + sx0);
            float arb  = 0.5f * (rb1 + rb0);
            float abx  = 0.5f * (bw1 * nx1 + bw0 * nx0);
            t = abb * kH2 * cx * lgx + arho * asx * cx * gux + arb * abx * cx * gux;
        }
        taux[b * NFACE + rem] = t;
    }
    if (cj < S-1) {
        float lap1 = sF[0][ty][tx+1], rho1 = sF[1][ty][tx+1], sy1 = sF[3][ty][tx+1];
        float c1 = sF[4][ty][tx+1], u1 = sF[5][ty][tx+1];
        float bb1 = sF[6][ty][tx+1], bw1 = sF[7][ty][tx+1];
        float cy = 2.f * c1 * c0 / (c1 + c0 + 1e-6f);
        cyP[(b << 18) + rem] = cy;
        float t = 0.f;
        if (ci > 0 && ci < S-1) {
            float guy = (u1 - u0) * kINVH;
            float lgy = (lap1 - lap0) * kINVH;
            float rb1 = rbT[rem + 1], ny1 = bnyT[rem + 1];
            float abb  = 0.5f * (bb1 + bb0);
            float arho = 0.5f * (rho1 + rho0);
            float asy  = 0.5f * (sy1 + sy0);
            float arb  = 0.5f * (rb1 + rb0);
            float aby  = 0.5f * (bw1 * ny1 + bw0 * ny0);
            t = abb * kH2 * cy * lgy + arho * asy * cy * guy + arb * aby * cy * guy;
        }
        tauyP[(b << 18) + rem] = t;
    }
}

// ---------- helpers ---------------------------------------------------------------
__device__ __forceinline__ void load8(const float* __restrict__ src, float (&v)[8]) {
    float4 a = *(const float4*)(src);
    float4 c = *(const float4*)(src + 4);
    v[0]=a.x; v[1]=a.y; v[2]=a.z; v[3]=a.w; v[4]=c.x; v[5]=c.y; v[6]=c.z; v[7]=c.w;
}
__device__ __forceinline__ void store8(float* __restrict__ dst, const float (&v)[8]) {
    float4 a, c;
    a.x=v[0]; a.y=v[1]; a.z=v[2]; a.w=v[3];
    c.x=v[4]; c.y=v[5]; c.z=v[6]; c.w=v[7];
    *(float4*)(dst) = a;
    *(float4*)(dst + 4) = c;
}
// LDS row accessors, transposed layout (2 lanes/bank = conflict-free).
__device__ __forceinline__ void lds_pub(float* sr, int lane, const float (&v)[8]) {
    #pragma unroll
    for (int m = 0; m < 8; ++m) sr[m*64 + lane] = v[m];
}
__device__ __forceinline__ void lds_row(const float* sr, int lane, float (&v)[8]) {
    #pragma unroll
    for (int m = 0; m < 8; ++m) v[m] = sr[m*64 + lane];
}

// ---------- coherent edge-row exchange (R4-proven path) ----------------------------
// Transposed layout: element (lane, m) of a 512-float row at [m*64 + lane].
// Relaxed agent-scope scalar atomics: per-access coherent (bypass to L3),
// no fences/flushes; one wave op = 64 consecutive dwords = full sector coverage.
__device__ __forceinline__ void coh_st_row(float* rowbuf, int lane, const float (&v)[8]) {
    #pragma unroll
    for (int m = 0; m < 8; ++m)
        __hip_atomic_store(rowbuf + m*64 + lane, v[m],
                           __ATOMIC_RELAXED, __HIP_MEMORY_SCOPE_AGENT);
}
__device__ __forceinline__ void coh_ld_row(const float* rowbuf, int lane, float (&v)[8]) {
    #pragma unroll
    for (int m = 0; m < 8; ++m)
        v[m] = __hip_atomic_load(rowbuf + m*64 + lane,
                                 __ATOMIC_RELAXED, __HIP_MEMORY_SCOPE_AGENT);
}

// ---------- per-batch grid barrier (64 blocks) — spread-arrival version ------------
// R8's barrier cost (~2.5us) was 64 relaxed adds convoying on ONE L3 line. Spread
// arrivals over 8 padded counters (8 arrivals each; block's counter = g&7); lanes
// 0..7 of wave 0 each poll one counter until >= 8*phase (divergent loop == __all).
// Same monotonic-phase semantics and drain-before-arrive structure as R4/R8
// (syncthreads emits vmcnt(0) -> all this block's stores L3-visible pre-arrival).
__device__ __forceinline__ void gbar(unsigned* cb, int myctr, unsigned ph) {
    __syncthreads();                       // drains vmcnt -> stores L3-visible
    if (threadIdx.x == 0)
        __hip_atomic_fetch_add(cb + (myctr << 4), 1u,
                               __ATOMIC_RELAXED, __HIP_MEMORY_SCOPE_AGENT);
    if (threadIdx.x < 8) {
        unsigned tgt = ph << 3;            // 8 arrivals per counter per phase
        long g = 0;
        while (__hip_atomic_load(cb + ((int)threadIdx.x << 4),
                                 __ATOMIC_RELAXED, __HIP_MEMORY_SCOPE_AGENT) < tgt) {
            __builtin_amdgcn_s_sleep(1);
            if (++g > (1L << 26)) break;   // fail loud, never hang
        }
    }
    __syncthreads();
}

// A(p) for this thread's 8 cells; nN/nS gathered by caller (LDS or coherent).
// Expression tree identical to verified k_iter -> bit-identical values.
__device__ __forceinline__ void apply_stencil2(
        bool rowInt, int j0, const float (&pv)[8],
        const float (&nN)[8], const float (&nS)[8],
        const float (&cxN)[8], const float (&cxS)[8],
        const float (&cyE)[8], float cyW0, float (&apv)[8]) {
    float pW = __shfl_up(pv[7], 1);   // lane l-1's east cell = my west neighbor
    float pE = __shfl_down(pv[0], 1);
    #pragma unroll
    for (int m = 0; m < 8; ++m) {
        int j = j0 + m;
        if (rowInt && j >= 1 && j <= S-2) {
            float pe  = (m < 7) ? pv[m+1] : pE;
            float pw  = (m > 0) ? pv[m-1] : pW;
            float cyw = (m > 0) ? cyE[m-1] : cyW0;
            float qxp = cxN[m] * ((nN[m] - pv[m]) * kINVH);
            float qxm = cxS[m] * ((pv[m] - nS[m]) * kINVH);
            float qyp = cyE[m] * ((pe - pv[m]) * kINVH);
            float qym = cyw   * ((pv[m] - pw) * kINVH);
            apv[m] = -((qxp - qxm) * kINVH + (qyp - qym) * kINVH);
        } else {
            apv[m] = pv[m];           // Dirichlet (boundary value is 0)
        }
    }
}

// ====== K_CG: persistent CG (R8 structure, proven) + spread-arrival barrier. =======
// 512 blocks x 512 thr (8 waves = 8-row strip; 64 strips/batch; 2 blocks/CU).
// Rows exchange within a block via LDS; only strip-edge rows cross blocks
// (transposed coherent buffers). x,r,p,ap,cx,cy live in REGISTERS for all 20
// iterations. 2 gbar/iteration.
__global__ __launch_bounds__(512, 4) void k_cg(
        const float* __restrict__ taux, const float* __restrict__ tauy,
        const float* __restrict__ cxP,  const float* __restrict__ cyP,
        const float* __restrict__ u,    float* __restrict__ out,
        float* __restrict__ prow, double* __restrict__ dots, unsigned* bar) {
    __shared__ double red[32];            // [0..3] scalar bcast; [8..31] partials
    __shared__ float srow[8][512];        // transposed p rows of this block's strip

    const int tid  = threadIdx.x;
    const int lane = tid & 63;
    const int w    = tid >> 6;            // 0..7
    const int bid  = blockIdx.x;
    const int b    = bid & 7;             // batch (XCD-local heuristic only)
    const int g    = bid >> 3;            // strip 0..63 within batch
    const int i    = (g << 3) + w;        // wave = row
    const int j0   = lane << 3;           // 8 cells per lane
    const bool rowInt = (i >= 1 && i <= S-2);
    const int base = (b << 18) + (i << 9) + j0;

    float* pubRow = prow + ((size_t)((bid << 1) | (w == 7 ? 1 : 0)) << 9);
    const bool pubEdge = (w == 0 && g > 0) || (w == 7 && g < 63);
    const float* haloS = prow + ((size_t)(((bid - 8) << 1) | 1) << 9);
    const float* haloN = prow + ((size_t)(((bid + 8) << 1) | 0) << 9);
    unsigned* cb   = bar + (b << 7);      // 8 padded counters for this batch
    const int myc  = g & 7;
    double* dslot  = dots + ((size_t)((b << 6) | g) << 2);   // [8][64][4]
    unsigned ph = 0;

    // ---- persistent coefficient registers (loaded once, normal cached reads) ----
    float cxN[8], cxS[8], cyE[8];
    float cyW0 = 0.f;
    #pragma unroll
    for (int m = 0; m < 8; ++m) { cxN[m] = 0.f; cxS[m] = 0.f; cyE[m] = 0.f; }
    if (rowInt) {
        const float* cxr = cxP + base;    // face-row i (north), i-1 (south)
        const float* cyr = cyP + base;
        load8(cxr,     cxN);
        load8(cxr - S, cxS);
        load8(cyr,     cyE);
        if (j0 > 0) cyW0 = cyr[-1];
    }

    // ---- persistent CG state ----
    float x[8], r[8], p[8], ap[8];
    #pragma unroll
    for (int m = 0; m < 8; ++m) { x[m]=0.f; r[m]=0.f; p[m]=0.f; ap[m]=0.f; }

    // ---- phase 0: rhs = div(tau); p0 = r0 = rhs (zb'ed); x = 0 ----
    if (rowInt) {
        const float* txr = taux + b * NFACE + (i << 9) + j0;
        const float* tyr = tauy + base;
        float tx0[8], txm[8], ty0[8];
        load8(txr,     tx0);
        load8(txr - S, txm);
        load8(tyr,     ty0);
        float tyW = __shfl_up(ty0[7], 1);
        #pragma unroll
        for (int m = 0; m < 8; ++m) {
            int j = j0 + m;
            if (j >= 1 && j <= S-2) {
                float tw = (m > 0) ? ty0[m-1] : tyW;
                r[m] = (tx0[m] - txm[m]) * kINVH + (ty0[m] - tw) * kINVH;
            }
            p[m] = r[m];
        }
    }
    lds_pub(srow[w], lane, p);
    if (pubEdge) coh_st_row(pubRow, lane, p);
    ++ph; gbar(cb, myc, ph);              // A0: p0 visible batch-wide

    // ---- ap0 = A(p0); dots {pap, rap=pap, apap, rr} ----
    {
        float nN[8], nS[8];
        #pragma unroll
        for (int m = 0; m < 8; ++m) { nN[m] = 0.f; nS[m] = 0.f; }
        if (rowInt) {
            if (w == 0) coh_ld_row(haloS, lane, nS);
            else        lds_row(srow[w-1], lane, nS);
            if (w == 7) coh_ld_row(haloN, lane, nN);
            else        lds_row(srow[w+1], lane, nN);
        }
        apply_stencil2(rowInt, j0, p, nN, nS, cxN, cxS, cyE, cyW0, ap);
        double d0 = 0.0, d2 = 0.0, d3 = 0.0;
        #pragma unroll
        for (int m = 0; m < 8; ++m) {
            d0 += (double)p[m]  * (double)ap[m];
            d2 += (double)ap[m] * (double)ap[m];
            d3 += (double)r[m]  * (double)r[m];
        }
        #pragma unroll
        for (int off = 32; off > 0; off >>= 1) {
            d0 += __shfl_down(d0, off, 64);
            d2 += __shfl_down(d2, off, 64);
            d3 += __shfl_down(d3, off, 64);
        }
        if (lane == 0) { red[8+w] = d0; red[16+w] = d2; red[24+w] = d3; }
        __syncthreads();
        if (tid == 0) {
            double t0=0, t2=0, t3=0;
            #pragma unroll
            for (int q = 0; q < 8; ++q) { t0 += red[8+q]; t2 += red[16+q]; t3 += red[24+q]; }
            __hip_atomic_store(dslot+0, t0, __ATOMIC_RELAXED, __HIP_MEMORY_SCOPE_AGENT);
            __hip_atomic_store(dslot+1, t0, __ATOMIC_RELAXED, __HIP_MEMORY_SCOPE_AGENT);
            __hip_atomic_store(dslot+2, t2, __ATOMIC_RELAXED, __HIP_MEMORY_SCOPE_AGENT);
            __hip_atomic_store(dslot+3, t3, __ATOMIC_RELAXED, __HIP_MEMORY_SCOPE_AGENT);
        }
    }
    ++ph; gbar(cb, myc, ph);              // B0: partials visible

    double rnCur = 0.0;
    for (int it = 1; it < CG_ITERS; ++it) {
        // ---- scalars: wave 0 reduces previous round's 64 partials ----
        if (w == 0) {
            const double* dr = dots + ((size_t)((b << 6) | lane) << 2);
            double s0 = __hip_atomic_load(dr+0, __ATOMIC_RELAXED, __HIP_MEMORY_SCOPE_AGENT);
            double s1 = __hip_atomic_load(dr+1, __ATOMIC_RELAXED, __HIP_MEMORY_SCOPE_AGENT);
            double s2 = __hip_atomic_load(dr+2, __ATOMIC_RELAXED, __HIP_MEMORY_SCOPE_AGENT);
            double s3 = (it == 1)
                ? __hip_atomic_load(dr+3, __ATOMIC_RELAXED, __HIP_MEMORY_SCOPE_AGENT) : 0.0;
            #pragma unroll
            for (int off = 32; off > 0; off >>= 1) {
                s0 += __shfl_down(s0, off, 64);
                s1 += __shfl_down(s1, off, 64);
                s2 += __shfl_down(s2, off, 64);
                s3 += __shfl_down(s3, off, 64);
            }
            if (lane == 0) { red[0]=s0; red[1]=s1; red[2]=s2; red[3]=s3; }
        }
        __syncthreads();
        double pap    = red[0];
        double rap    = red[1];
        double apap   = red[2];
        double rnPrev = (it == 1) ? red[3] : rnCur;
        float alphaF = (float)(rnPrev / fmax(pap, 1e-6));
        double aD = (double)alphaF;
        rnCur = rnPrev - 2.0 * aD * rap + aD * aD * apap;
        float betaF = (float)(rnCur / fmax(rnPrev, 1e-6));

        // ---- vector updates (all in registers) ----
        #pragma unroll
        for (int m = 0; m < 8; ++m) {
            x[m] += alphaF * p[m];
            r[m]  = r[m] - alphaF * ap[m];
            p[m]  = r[m] + betaF * p[m];
        }
        lds_pub(srow[w], lane, p);        // srow reads of prev round done pre-gbar B
        if (pubEdge) coh_st_row(pubRow, lane, p);
        ++ph; gbar(cb, myc, ph);          // A: new p visible

        // ---- ap = A(p); dots {pap, rap, apap} ----
        float nN[8], nS[8];
        #pragma unroll
        for (int m = 0; m < 8; ++m) { nN[m] = 0.f; nS[m] = 0.f; }
        if (rowInt) {
            if (w == 0) coh_ld_row(haloS, lane, nS);
            else        lds_row(srow[w-1], lane, nS);
            if (w == 7) coh_ld_row(haloN, lane, nN);
            else        lds_row(srow[w+1], lane, nN);
        }
        apply_stencil2(rowInt, j0, p, nN, nS, cxN, cxS, cyE, cyW0, ap);
        double d0 = 0.0, d1 = 0.0, d2 = 0.0;
        #pragma unroll
        for (int m = 0; m < 8; ++m) {
            d0 += (double)p[m]  * (double)ap[m];
            d1 += (double)r[m]  * (double)ap[m];
            d2 += (double)ap[m] * (double)ap[m];
        }
        #pragma unroll
        for (int off = 32; off > 0; off >>= 1) {
            d0 += __shfl_down(d0, off, 64);
            d1 += __shfl_down(d1, off, 64);
            d2 += __shfl_down(d2, off, 64);
        }
        if (lane == 0) { red[8+w] = d0; red[16+w] = d1; red[24+w] = d2; }
        __syncthreads();
        if (tid == 0) {
            double t0=0, t1=0, t2=0;
            #pragma unroll
            for (int q = 0; q < 8; ++q) { t0 += red[8+q]; t1 += red[16+q]; t2 += red[24+q]; }
            __hip_atomic_store(dslot+0, t0, __ATOMIC_RELAXED, __HIP_MEMORY_SCOPE_AGENT);
            __hip_atomic_store(dslot+1, t1, __ATOMIC_RELAXED, __HIP_MEMORY_SCOPE_AGENT);
            __hip_atomic_store(dslot+2, t2, __ATOMIC_RELAXED, __HIP_MEMORY_SCOPE_AGENT);
        }
        ++ph; gbar(cb, myc, ph);          // B: partials visible
    }

    // ---- finale: alpha_19 = rn_19 / pap_19; out = zb(u + x + alpha*p) ----
    {
        if (w == 0) {
            const double* dr = dots + ((size_t)((b << 6) | lane) << 2);
            double s0 = __hip_atomic_load(dr+0, __ATOMIC_RELAXED, __HIP_MEMORY_SCOPE_AGENT);
            #pragma unroll
            for (int off = 32; off > 0; off >>= 1) s0 += __shfl_down(s0, off, 64);
            if (lane == 0) red[0] = s0;
        }
        __syncthreads();
        double pap = red[0];
        float alphaF = (float)(rnCur / fmax(pap, 1e-6));
        float o[8];
        #pragma unroll
        for (int m = 0; m < 8; ++m) o[m] = 0.f;
        if (rowInt) {
            float uu[8];
            load8(u + base, uu);
            #pragma unroll
            for (int m = 0; m < 8; ++m) {
                int j = j0 + m;
                if (j >= 1 && j <= S-2) o[m] = uu[m] + x[m] + alphaF * p[m];
            }
        }
        store8(out + base, o);
    }
}

extern "C" void kernel_launch(void* const* d_in, const int* in_sizes, int n_in,
                              void* d_out, int out_size, void* d_ws, size_t ws_size,
                              hipStream_t stream) {
    const float* coeff = (const float*)d_in[0];
    const float* u     = (const float*)d_in[1];
    const float* beta  = (const float*)d_in[2];
    float* out = (float*)d_out;

    float* ws    = (float*)d_ws;
    float* tauxB = ws;                    // NTOT (b-stride NFACE inside)
    float* tauyB = ws + (size_t)NTOT;
    float* cxB   = ws + 2*(size_t)NTOT;
    float* cyB   = ws + 3*(size_t)NTOT;
    float* prow  = ws + 4*(size_t)NTOT;   // [512 blocks][2 edges][512] floats
    double* dots = (double*)(prow + (size_t)NBLK3*2*512);   // [8][64][4] doubles
    unsigned* bar = (unsigned*)(dots + 8*64*4);             // 8x8 padded counters
    float* rbT   = (float*)(bar + 1024);  // geometry tables, NCELL each
    float* bnxT  = rbT + NCELL;
    float* bnyT  = bnxT + NCELL;

    // barrier counters must start at 0 (monotonic within one launch)
    (void)hipMemsetAsync(bar, 0, 4096, stream);

    k_geom<<<1024, dim3(256), 0, stream>>>(rbT, bnxT, bnyT);
    k_setup<<<8192, dim3(256), 0, stream>>>(coeff, u, beta, rbT, bnxT, bnyT,
                                            tauxB, tauyB, cxB, cyB);
    k_cg<<<NBLK3, dim3(512), 0, stream>>>(tauxB, tauyB, cxB, cyB, u, out,
                                          prow, dots, bar);
}

// Round 11
// 338.455 us; speedup vs baseline: 1.0316x; 1.0316x over previous
//
#include <hip/hip_runtime.h>
#include <math.h>

// Problem constants (match reference)
#define S     512
#define Bsz   8
#define NCELL (S*S)              // 262144 = 2^18
#define NTOT  (Bsz*NCELL)        // 2097152
#define NFACE ((S-1)*S)          // 261632
#define CG_ITERS 20
#define NBLK3 512                // persistent grid: 64 blocks/batch, 8 rows/block
#define TS    16                 // k_setup tile

__device__ __constant__ float kINVH  = 511.0f;     // 1/h
__device__ __constant__ float kINV2H = 255.5f;
__device__ __constant__ float kH2    = (float)((1.0/511.0)*(1.0/511.0));

// ---------------- geometry (replicates numpy grid_helpers bit-exactly in double) ----
__device__ __forceinline__ void geom(int i, int j, float& rhob, float& bnx, float& bny) {
    double gx = (i == S-1) ? 1.0 : (double)i * (1.0/511.0);
    double gy = (j == S-1) ? 1.0 : (double)j * (1.0/511.0);
    double v0 = gx, v1 = 1.0 - gx, v2 = gy, v3 = 1.0 - gy;
    double m = v0; int am = 0;
    if (v1 < m) { m = v1; am = 1; }   // strict '<' == np.argmin first-min-wins
    if (v2 < m) { m = v2; am = 2; }
    if (v3 < m) { m = v3; am = 3; }
    float d = (float)m;
    rhob = expf(-(d*d) / 0.0225f);
    bnx = (am == 0) ? -1.f : (am == 1) ? 1.f : 0.f;
    bny = (am == 2) ? -1.f : (am == 3) ? 1.f : 0.f;
}

// ---- per-cell fields; expressions identical to verified pipeline ------------------
__device__ __forceinline__ void cellfield8(const float* __restrict__ c,
                                           const float* __restrict__ uu,
                                           const float* __restrict__ bb,
                                           int i, int j, float* f) {
    int rem = i * S + j;
    float cc = c[rem];
    float uc = uu[rem];
    float lapv = 0.f;
    if (i > 0 && i < S-1 && j > 0 && j < S-1) {
        float un = uu[rem + S], us = uu[rem - S];
        float ue = uu[rem + 1], uw = uu[rem - 1];
        lapv = ((un - uc)*kINVH - (uc - us)*kINVH)*kINVH
             + ((ue - uc)*kINVH - (uc - uw)*kINVH)*kINVH;
    }
    float glx, gly;
    float lc = logf(fmaxf(cc, 1e-6f));
    if (i == 0)        { glx = (logf(fmaxf(c[rem+S],1e-6f)) - lc) * kINVH; }
    else if (i == S-1) { glx = (lc - logf(fmaxf(c[rem-S],1e-6f))) * kINVH; }
    else { glx = (logf(fmaxf(c[rem+S],1e-6f)) - logf(fmaxf(c[rem-S],1e-6f))) * kINV2H; }
    if (j == 0)        { gly = (logf(fmaxf(c[rem+1],1e-6f)) - lc) * kINVH; }
    else if (j == S-1) { gly = (lc - logf(fmaxf(c[rem-1],1e-6f))) * kINVH; }
    else { gly = (logf(fmaxf(c[rem+1],1e-6f)) - logf(fmaxf(c[rem-1],1e-6f))) * kINV2H; }
    float eta  = sqrtf(glx*glx + gly*gly + 1e-6f);
    float rhov = 1.f / (1.f + expf(-10.f * (eta - 0.5f)));
    float nhx = glx / eta, nhy = gly / eta;
    float4 b4 = ((const float4*)bb)[rem];
    f[0] = lapv; f[1] = rhov;
    f[2] = b4.y * nhx - b4.z * nhy;
    f[3] = b4.y * nhy + b4.z * nhx;
    f[4] = cc; f[5] = uc; f[6] = b4.x; f[7] = b4.w;
}

// ========== K_SETUP: R8 version verbatim (inline geom; absmax-proven) ==============
__global__ __launch_bounds__(256) void k_setup(
        const float* __restrict__ coeff, const float* __restrict__ u,
        const float* __restrict__ beta,
        float* __restrict__ taux, float* __restrict__ tauyP,
        float* __restrict__ cxP, float* __restrict__ cyP) {
    __shared__ float sF[8][TS+1][TS+8];
    int b  = blockIdx.x >> 10;
    int tl = blockIdx.x & 1023;
    int i0 = (tl >> 5) << 4;
    int j0 = (tl & 31) << 4;
    int tx = threadIdx.x & 15, ty = threadIdx.x >> 4;
    const float* cB = coeff + (b << 18);
    const float* uB = u     + (b << 18);
    const float* bB = beta  + ((size_t)b << 20);

    {   float f[8];
        cellfield8(cB, uB, bB, i0 + ty, j0 + tx, f);
        #pragma unroll
        for (int q = 0; q < 8; ++q) sF[q][ty][tx] = f[q];
    }
    if (threadIdx.x < 16 && i0 + TS < S) {
        float f[8];
        cellfield8(cB, uB, bB, i0 + TS, j0 + threadIdx.x, f);
        #pragma unroll
        for (int q = 0; q < 8; ++q) sF[q][TS][threadIdx.x] = f[q];
    }
    if (threadIdx.x >= 64 && threadIdx.x < 80 && j0 + TS < S) {
        int k = threadIdx.x - 64;
        float f[8];
        cellfield8(cB, uB, bB, i0 + k, j0 + TS, f);
        #pragma unroll
        for (int q = 0; q < 8; ++q) sF[q][k][TS] = f[q];
    }
    __syncthreads();

    int ci = i0 + ty, cj = j0 + tx;
    int rem = ci * S + cj;
    float lap0 = sF[0][ty][tx], rho0 = sF[1][ty][tx];
    float sx0  = sF[2][ty][tx], sy0  = sF[3][ty][tx];
    float c0   = sF[4][ty][tx], u0   = sF[5][ty][tx];
    float bb0  = sF[6][ty][tx], bw0  = sF[7][ty][tx];
    float rb0, nx0, ny0; geom(ci, cj, rb0, nx0, ny0);

    if (ci < S-1) {
        float lap1 = sF[0][ty+1][tx], rho1 = sF[1][ty+1][tx], sx1 = sF[2][ty+1][tx];
        float c1 = sF[4][ty+1][tx], u1 = sF[5][ty+1][tx];
        float bb1 = sF[6][ty+1][tx], bw1 = sF[7][ty+1][tx];
        float cx = 2.f * c1 * c0 / (c1 + c0 + 1e-6f);
        cxP[(b << 18) + rem] = cx;
        float t = 0.f;
        if (cj > 0 && cj < S-1) {
            float gux = (u1 - u0) * kINVH;
            float lgx = (lap1 - lap0) * kINVH;
            float rb1, nx1, ny1; geom(ci+1, cj, rb1, nx1, ny1);
            float abb  = 0.5f * (bb1 + bb0);
            float arho = 0.5f * (rho1 + rho0);
            float asx  = 0.5f * (sx1 + sx0);
            float arb  = 0.5f * (rb1 + rb0);
            float abx  = 0.5f * (bw1 * nx1 + bw0 * nx0);
            t = abb * kH2 * cx * lgx + arho * asx * cx * gux + arb * abx * cx * gux;
        }
        taux[b * NFACE + rem] = t;
    }
    if (cj < S-1) {
        float lap1 = sF[0][ty][tx+1], rho1 = sF[1][ty][tx+1], sy1 = sF[3][ty][tx+1];
        float c1 = sF[4][ty][tx+1], u1 = sF[5][ty][tx+1];
        float bb1 = sF[6][ty][tx+1], bw1 = sF[7][ty][tx+1];
        float cy = 2.f * c1 * c0 / (c1 + c0 + 1e-6f);
        cyP[(b << 18) + rem] = cy;
        float t = 0.f;
        if (ci > 0 && ci < S-1) {
            float guy = (u1 - u0) * kINVH;
            float lgy = (lap1 - lap0) * kINVH;
            float rb1, nx1, ny1; geom(ci, cj+1, rb1, nx1, ny1);
            float abb  = 0.5f * (bb1 + bb0);
            float arho = 0.5f * (rho1 + rho0);
            float asy  = 0.5f * (sy1 + sy0);
            float arb  = 0.5f * (rb1 + rb0);
            float aby  = 0.5f * (bw1 * ny1 + bw0 * ny0);
            t = abb * kH2 * cy * lgy + arho * asy * cy * guy + arb * aby * cy * guy;
        }
        tauyP[(b << 18) + rem] = t;
    }
}

// ---------- helpers ---------------------------------------------------------------
__device__ __forceinline__ void load8(const float* __restrict__ src, float (&v)[8]) {
    float4 a = *(const float4*)(src);
    float4 c = *(const float4*)(src + 4);
    v[0]=a.x; v[1]=a.y; v[2]=a.z; v[3]=a.w; v[4]=c.x; v[5]=c.y; v[6]=c.z; v[7]=c.w;
}
__device__ __forceinline__ void store8(float* __restrict__ dst, const float (&v)[8]) {
    float4 a, c;
    a.x=v[0]; a.y=v[1]; a.z=v[2]; a.w=v[3];
    c.x=v[4]; c.y=v[5]; c.z=v[6]; c.w=v[7];
    *(float4*)(dst) = a;
    *(float4*)(dst + 4) = c;
}
// LDS row accessors, transposed layout (2 lanes/bank = conflict-free).
__device__ __forceinline__ void lds_pub(float* sr, int lane, const float (&v)[8]) {
    #pragma unroll
    for (int m = 0; m < 8; ++m) sr[m*64 + lane] = v[m];
}
__device__ __forceinline__ void lds_row(const float* sr, int lane, float (&v)[8]) {
    #pragma unroll
    for (int m = 0; m < 8; ++m) v[m] = sr[m*64 + lane];
}

// ---------- coherent edge-row exchange (R4/R8-proven path) -------------------------
// Transposed layout: element (lane, m) of a 512-float row at [m*64 + lane].
__device__ __forceinline__ void coh_st_row(float* rowbuf, int lane, const float (&v)[8]) {
    #pragma unroll
    for (int m = 0; m < 8; ++m)
        __hip_atomic_store(rowbuf + m*64 + lane, v[m],
                           __ATOMIC_RELAXED, __HIP_MEMORY_SCOPE_AGENT);
}
__device__ __forceinline__ void coh_ld_row(const float* rowbuf, int lane, float (&v)[8]) {
    #pragma unroll
    for (int m = 0; m < 8; ++m)
        v[m] = __hip_atomic_load(rowbuf + m*64 + lane,
                                 __ATOMIC_RELAXED, __HIP_MEMORY_SCOPE_AGENT);
}

// ---------- per-batch grid barrier (64 blocks) — R8-proven EXACTLY -----------------
// R9 lesson: spreading arrivals over 8 counters with 8 pollers/block REGRESSED
// (poll pressure slows release propagation). Single counter, one poller per block.
__device__ __forceinline__ void gbar(unsigned* ctr, unsigned tgt) {
    __syncthreads();                       // drains vmcnt -> stores L3-visible
    if (threadIdx.x == 0) {
        __hip_atomic_fetch_add(ctr, 1u, __ATOMIC_RELAXED, __HIP_MEMORY_SCOPE_AGENT);
        long g = 0;
        while (__hip_atomic_load(ctr, __ATOMIC_RELAXED, __HIP_MEMORY_SCOPE_AGENT) < tgt) {
            __builtin_amdgcn_s_sleep(2);
            if (++g > (1L << 26)) break;
        }
    }
    __syncthreads();
}

// A(p) for this thread's 8 cells; nN/nS gathered by caller (LDS or registers).
// Expression tree identical to verified k_iter -> bit-identical values.
__device__ __forceinline__ void apply_stencil2(
        bool rowInt, int j0, const float (&pv)[8],
        const float (&nN)[8], const float (&nS)[8],
        const float (&cxN)[8], const float (&cxS)[8],
        const float (&cyE)[8], float cyW0, float (&apv)[8]) {
    float pW = __shfl_up(pv[7], 1);   // lane l-1's east cell = my west neighbor
    float pE = __shfl_down(pv[0], 1);
    #pragma unroll
    for (int m = 0; m < 8; ++m) {
        int j = j0 + m;
        if (rowInt && j >= 1 && j <= S-2) {
            float pe  = (m < 7) ? pv[m+1] : pE;
            float pw  = (m > 0) ? pv[m-1] : pW;
            float cyw = (m > 0) ? cyE[m-1] : cyW0;
            float qxp = cxN[m] * ((nN[m] - pv[m]) * kINVH);
            float qxm = cxS[m] * ((pv[m] - nS[m]) * kINVH);
            float qyp = cyE[m] * ((pe - pv[m]) * kINVH);
            float qym = cyw   * ((pv[m] - pw) * kINVH);
            apv[m] = -((qxp - qxm) * kINVH + (qyp - qym) * kINVH);
        } else {
            apv[m] = pv[m];           // Dirichlet (boundary value is 0)
        }
    }
}

// ====== K_CG: ONE barrier per iteration via edge-row reconstruction. ==============
// 512 blocks x 512 thr (R8 geometry, proven). Each round publishes {ap edge rows,
// dot partials} once, then one barrier. After scalars, edge waves RECONSTRUCT the
// neighbor's new edge p locally: rN -= alpha*apN; pN = rN + beta*pN — identical
// float ops on identical bits as the neighbor's own update -> bit-exact
// (alpha/beta identical across blocks: same doubles, fixed reduction order).
// Seeded from the p0-edge publish. Parity double-buffering of apE and dots makes
// WAR barrier-provable: round-R parity-P reads happen in (bar R, bar R+1); the
// next parity-P write is after bar R+1. Barriers: 1 + 20 = 21 (was 40).
__global__ __launch_bounds__(512, 4) void k_cg(
        const float* __restrict__ taux, const float* __restrict__ tauy,
        const float* __restrict__ cxP,  const float* __restrict__ cyP,
        const float* __restrict__ u,    float* __restrict__ out,
        float* __restrict__ pinit, float* __restrict__ apE,
        double* __restrict__ dots, unsigned* bar) {
    __shared__ double red[32];            // [0..3] scalar bcast; [8..31] partials
    __shared__ float srow[8][512];        // transposed p rows of this block's strip

    const int tid  = threadIdx.x;
    const int lane = tid & 63;
    const int w    = tid >> 6;            // 0..7
    const int bid  = blockIdx.x;
    const int b    = bid & 7;             // batch (XCD-local heuristic only)
    const int g    = bid >> 3;            // strip 0..63 within batch
    const int i    = (g << 3) + w;        // wave = row
    const int j0   = lane << 3;           // 8 cells per lane
    const bool rowInt = (i >= 1 && i <= S-2);
    const int base = (b << 18) + (i << 9) + j0;

    const size_t APB = (size_t)NBLK3 * 2 * 512;    // floats per apE parity
    const size_t pubOff  = (size_t)((bid << 1) | (w == 7 ? 1 : 0)) << 9;
    const bool isS = (w == 0 && g > 0);   // south edge wave (has S neighbor)
    const bool isN = (w == 7 && g < 63);  // north edge wave (has N neighbor)
    const bool pubEdge = isS || isN;
    const size_t nbOff = isS ? ((size_t)(((bid - 8) << 1) | 1) << 9)
                             : ((size_t)(((bid + 8) << 1) | 0) << 9);
    unsigned* ctr = bar + (b << 4);       // 64B-padded counter per batch
    unsigned ph = 0;

    // ---- persistent coefficient registers (loaded once, normal cached reads) ----
    float cxN[8], cxS[8], cyE[8];
    float cyW0 = 0.f;
    #pragma unroll
    for (int m = 0; m < 8; ++m) { cxN[m] = 0.f; cxS[m] = 0.f; cyE[m] = 0.f; }
    if (rowInt) {
        const float* cxr = cxP + base;    // face-row i (north), i-1 (south)
        const float* cyr = cyP + base;
        load8(cxr,     cxN);
        load8(cxr - S, cxS);
        load8(cyr,     cyE);
        if (j0 > 0) cyW0 = cyr[-1];
    }

    // ---- persistent CG state (+ neighbor edge-row mirror for edge waves) ----
    float x[8], r[8], p[8], ap[8], pN8[8], rN8[8];
    #pragma unroll
    for (int m = 0; m < 8; ++m) { x[m]=0.f; r[m]=0.f; p[m]=0.f; ap[m]=0.f;
                                  pN8[m]=0.f; rN8[m]=0.f; }

    // ---- phase 0: rhs = div(tau); p0 = r0 = rhs (zb'ed); x = 0 ----
    if (rowInt) {
        const float* txr = taux + b * NFACE + (i << 9) + j0;
        const float* tyr = tauy + base;
        float tx0[8], txm[8], ty0[8];
        load8(txr,     tx0);
        load8(txr - S, txm);
        load8(tyr,     ty0);
        float tyW = __shfl_up(ty0[7], 1);
        #pragma unroll
        for (int m = 0; m < 8; ++m) {
            int j = j0 + m;
            if (j >= 1 && j <= S-2) {
                float tw = (m > 0) ? ty0[m-1] : tyW;
                r[m] = (tx0[m] - txm[m]) * kINVH + (ty0[m] - tw) * kINVH;
            }
            p[m] = r[m];
        }
    }
    lds_pub(srow[w], lane, p);
    if (pubEdge) coh_st_row(pinit + pubOff, lane, p);
    ++ph; gbar(ctr, ph << 6);             // A0: p0 edges visible batch-wide

    // seed neighbor edge mirror: pN = rN = neighbor's p0 edge row
    if (pubEdge) {
        coh_ld_row(pinit + nbOff, lane, pN8);
        for (int m = 0; m < 8; ++m) rN8[m] = pN8[m];
    }

    double rnCur = 0.0;
    float alphaL = 0.f;
    for (int rd = 0; rd < CG_ITERS; ++rd) {
        const int par = rd & 1;
        float* apPar = apE + (size_t)par * APB;

        // ---- stencil: neighbor rows from LDS or the register mirror ----
        float nN[8], nS[8];
        #pragma unroll
        for (int m = 0; m < 8; ++m) { nN[m] = 0.f; nS[m] = 0.f; }
        if (rowInt) {
            if (w == 0) {
                if (isS) {
                    for (int m = 0; m < 8; ++m) nS[m] = pN8[m];
                }
            } else {
                lds_row(srow[w-1], lane, nS);
            }
            if (w == 7) {
                if (isN) {
                    for (int m = 0; m < 8; ++m) nN[m] = pN8[m];
                }
            } else {
                lds_row(srow[w+1], lane, nN);
            }
        }
        apply_stencil2(rowInt, j0, p, nN, nS, cxN, cxS, cyE, cyW0, ap);

        // ---- dot partials (rd 0: rap=pap, +rr) ----
        double d0 = 0.0, d1 = 0.0, d2 = 0.0, d3 = 0.0;
        #pragma unroll
        for (int m = 0; m < 8; ++m) {
            d0 += (double)p[m]  * (double)ap[m];
            d2 += (double)ap[m] * (double)ap[m];
        }
        if (rd == 0) {
            #pragma unroll
            for (int m = 0; m < 8; ++m) d3 += (double)r[m] * (double)r[m];
            d1 = d0;
        } else {
            #pragma unroll
            for (int m = 0; m < 8; ++m) d1 += (double)r[m] * (double)ap[m];
        }
        #pragma unroll
        for (int off = 32; off > 0; off >>= 1) {
            d0 += __shfl_down(d0, off, 64);
            d1 += __shfl_down(d1, off, 64);
            d2 += __shfl_down(d2, off, 64);
            d3 += __shfl_down(d3, off, 64);
        }
        if (lane == 0) { red[8+w] = d0; red[16+w] = d1; red[24+w] = d2;
                         if (rd == 0) red[w] = d3; }
        __syncthreads();
        if (tid == 0) {
            double t0=0, t1=0, t2=0, t3=0;
            #pragma unroll
            for (int q = 0; q < 8; ++q) { t0 += red[8+q]; t1 += red[16+q];
                                          t2 += red[24+q]; if (rd == 0) t3 += red[q]; }
            double* dw = dots + ((size_t)((par << 9) + (b << 6) + g) << 2);
            __hip_atomic_store(dw+0, t0, __ATOMIC_RELAXED, __HIP_MEMORY_SCOPE_AGENT);
            __hip_atomic_store(dw+1, t1, __ATOMIC_RELAXED, __HIP_MEMORY_SCOPE_AGENT);
            __hip_atomic_store(dw+2, t2, __ATOMIC_RELAXED, __HIP_MEMORY_SCOPE_AGENT);
            if (rd == 0)
                __hip_atomic_store(dw+3, t3, __ATOMIC_RELAXED, __HIP_MEMORY_SCOPE_AGENT);
        }
        // ---- publish ap edge rows (parity buffer) ----
        if (pubEdge) coh_st_row(apPar + pubOff, lane, ap);
        ++ph; gbar(ctr, ph << 6);         // THE one barrier of this round

        // ---- scalars: wave 0 reduces this round's 64 partials ----
        if (w == 0) {
            const double* dr = dots + ((size_t)((par << 9) + (b << 6) + lane) << 2);
            double s0 = __hip_atomic_load(dr+0, __ATOMIC_RELAXED, __HIP_MEMORY_SCOPE_AGENT);
            double s1 = __hip_atomic_load(dr+1, __ATOMIC_RELAXED, __HIP_MEMORY_SCOPE_AGENT);
            double s2 = __hip_atomic_load(dr+2, __ATOMIC_RELAXED, __HIP_MEMORY_SCOPE_AGENT);
            double s3 = (rd == 0)
                ? __hip_atomic_load(dr+3, __ATOMIC_RELAXED, __HIP_MEMORY_SCOPE_AGENT) : 0.0;
            #pragma unroll
            for (int off = 32; off > 0; off >>= 1) {
                s0 += __shfl_down(s0, off, 64);
                s1 += __shfl_down(s1, off, 64);
                s2 += __shfl_down(s2, off, 64);
                s3 += __shfl_down(s3, off, 64);
            }
            if (lane == 0) { red[0]=s0; red[1]=s1; red[2]=s2; red[3]=s3; }
        }
        __syncthreads();
        double pap    = red[0];
        double rap    = red[1];
        double apap   = red[2];
        double rnPrev = (rd == 0) ? red[3] : rnCur;
        float alphaF = (float)(rnPrev / fmax(pap, 1e-6));
        double aD = (double)alphaF;
        rnCur = rnPrev - 2.0 * aD * rap + aD * aD * apap;
        float betaF = (float)(rnCur / fmax(rnPrev, 1e-6));

        if (rd == CG_ITERS - 1) { alphaL = alphaF; break; }

        // ---- update own state (registers) ----
        #pragma unroll
        for (int m = 0; m < 8; ++m) {
            x[m] += alphaF * p[m];
            r[m]  = r[m] - alphaF * ap[m];
            p[m]  = r[m] + betaF * p[m];
        }
        lds_pub(srow[w], lane, p);

        // ---- reconstruct neighbor edge p (bit-exact mirror of its own update) ----
        if (pubEdge) {
            float apN[8];
            coh_ld_row(apPar + nbOff, lane, apN);
            #pragma unroll
            for (int m = 0; m < 8; ++m) {
                rN8[m] = rN8[m] - alphaF * apN[m];
                pN8[m] = rN8[m] + betaF * pN8[m];
            }
        }
        __syncthreads();                  // new srow visible before next stencil
    }

    // ---- finale: out = zb(u + x + alpha_19 * p) ----
    {
        float o[8];
        #pragma unroll
        for (int m = 0; m < 8; ++m) o[m] = 0.f;
        if (rowInt) {
            float uu[8];
            load8(u + base, uu);
            #pragma unroll
            for (int m = 0; m < 8; ++m) {
                int j = j0 + m;
                if (j >= 1 && j <= S-2) o[m] = uu[m] + x[m] + alphaL * p[m];
            }
        }
        store8(out + base, o);
    }
}

extern "C" void kernel_launch(void* const* d_in, const int* in_sizes, int n_in,
                              void* d_out, int out_size, void* d_ws, size_t ws_size,
                              hipStream_t stream) {
    const float* coeff = (const float*)d_in[0];
    const float* u     = (const float*)d_in[1];
    const float* beta  = (const float*)d_in[2];
    float* out = (float*)d_out;

    float* ws    = (float*)d_ws;
    float* tauxB = ws;                    // NTOT (b-stride NFACE inside)
    float* tauyB = ws + (size_t)NTOT;
    float* cxB   = ws + 2*(size_t)NTOT;
    float* cyB   = ws + 3*(size_t)NTOT;
    float* pinit = ws + 4*(size_t)NTOT;                     // [512][2][512]
    float* apE   = pinit + (size_t)NBLK3*2*512;             // [2][512][2][512]
    double* dots = (double*)(apE + 2*(size_t)NBLK3*2*512);  // [2][8][64][4]
    unsigned* bar = (unsigned*)(dots + 2*8*64*4);           // 8 padded counters

    // barrier counters must start at 0 (monotonic within one launch)
    (void)hipMemsetAsync(bar, 0, 4096, stream);

    k_setup<<<8192, dim3(256), 0, stream>>>(coeff, u, beta, tauxB, tauyB, cxB, cyB);
    k_cg<<<NBLK3, dim3(512), 0, stream>>>(tauxB, tauyB, cxB, cyB, u, out,
                                          pinit, apE, dots, bar);
}

// Round 12
// 270.330 us; speedup vs baseline: 1.2916x; 1.2520x over previous
//
#include <hip/hip_runtime.h>
#include <math.h>

// Problem constants (match reference)
#define S     512
#define Bsz   8
#define NCELL (S*S)              // 262144 = 2^18
#define NTOT  (Bsz*NCELL)        // 2097152
#define NFACE ((S-1)*S)          // 261632
#define CG_ITERS 20
#define NBLK3 512                // persistent grid: 64 blocks/batch, 8 rows/block
#define TS    16                 // k_setup tile

__device__ __constant__ float kINVH  = 511.0f;     // 1/h
__device__ __constant__ float kINV2H = 255.5f;
__device__ __constant__ float kH2    = (float)((1.0/511.0)*(1.0/511.0));

// ---------------- geometry (replicates numpy grid_helpers bit-exactly in double) ----
__device__ __forceinline__ void geom(int i, int j, float& rhob, float& bnx, float& bny) {
    double gx = (i == S-1) ? 1.0 : (double)i * (1.0/511.0);
    double gy = (j == S-1) ? 1.0 : (double)j * (1.0/511.0);
    double v0 = gx, v1 = 1.0 - gx, v2 = gy, v3 = 1.0 - gy;
    double m = v0; int am = 0;
    if (v1 < m) { m = v1; am = 1; }   // strict '<' == np.argmin first-min-wins
    if (v2 < m) { m = v2; am = 2; }
    if (v3 < m) { m = v3; am = 3; }
    float d = (float)m;
    rhob = expf(-(d*d) / 0.0225f);
    bnx = (am == 0) ? -1.f : (am == 1) ? 1.f : 0.f;
    bny = (am == 2) ? -1.f : (am == 3) ? 1.f : 0.f;
}

// ---- per-cell fields, logf read from staged LDS tile -------------------------------
// sL[li][lj] = logf(fmaxf(c[(i0-1+li)*S + (j0-1+lj)], 1e-6f)) — same bits as the
// inline computation, so glx/gly (and everything downstream) are bit-identical.
__device__ __forceinline__ void cellfield8_lds(const float* __restrict__ c,
                                               const float* __restrict__ uu,
                                               const float* __restrict__ bb,
                                               const float (&sL)[19][20],
                                               int li, int lj,
                                               int i, int j, float* f) {
    int rem = i * S + j;
    float cc = c[rem];
    float uc = uu[rem];
    float lapv = 0.f;
    if (i > 0 && i < S-1 && j > 0 && j < S-1) {
        float un = uu[rem + S], us = uu[rem - S];
        float ue = uu[rem + 1], uw = uu[rem - 1];
        lapv = ((un - uc)*kINVH - (uc - us)*kINVH)*kINVH
             + ((ue - uc)*kINVH - (uc - uw)*kINVH)*kINVH;
    }
    float lc = sL[li][lj];
    float glx, gly;
    if (i == 0)        { glx = (sL[li+1][lj] - lc) * kINVH; }
    else if (i == S-1) { glx = (lc - sL[li-1][lj]) * kINVH; }
    else               { glx = (sL[li+1][lj] - sL[li-1][lj]) * kINV2H; }
    if (j == 0)        { gly = (sL[li][lj+1] - lc) * kINVH; }
    else if (j == S-1) { gly = (lc - sL[li][lj-1]) * kINVH; }
    else               { gly = (sL[li][lj+1] - sL[li][lj-1]) * kINV2H; }
    float eta  = sqrtf(glx*glx + gly*gly + 1e-6f);
    float rhov = 1.f / (1.f + expf(-10.f * (eta - 0.5f)));
    float nhx = glx / eta, nhy = gly / eta;
    float4 b4 = ((const float4*)bb)[rem];
    f[0] = lapv; f[1] = rhov;
    f[2] = b4.y * nhx - b4.z * nhy;
    f[3] = b4.y * nhy + b4.z * nhx;
    f[4] = cc; f[5] = uc; f[6] = b4.x; f[7] = b4.w;
}

// ========== K_SETUP: logc staged in LDS (5x fewer logf); geom inline (R8-proven) ===
__global__ __launch_bounds__(256) void k_setup(
        const float* __restrict__ coeff, const float* __restrict__ u,
        const float* __restrict__ beta,
        float* __restrict__ taux, float* __restrict__ tauyP,
        float* __restrict__ cxP, float* __restrict__ cyP) {
    __shared__ float sF[8][TS+1][TS+8];
    __shared__ float sLog[19][20];        // logc for rows i0-1..i0+17, cols j0-1..j0+17
    int b  = blockIdx.x >> 10;
    int tl = blockIdx.x & 1023;
    int i0 = (tl >> 5) << 4;
    int j0 = (tl & 31) << 4;
    int tx = threadIdx.x & 15, ty = threadIdx.x >> 4;
    const float* cB = coeff + (b << 18);
    const float* uB = u     + (b << 18);
    const float* bB = beta  + ((size_t)b << 20);

    // Phase A: stage logc for the 19x19 halo'd tile (1 logf per position)
    for (int t = threadIdx.x; t < 19*19; t += 256) {
        int li = t / 19, lj = t % 19;
        int gi = i0 - 1 + li, gj = j0 - 1 + lj;
        float v = 0.f;
        if (gi >= 0 && gi < S && gj >= 0 && gj < S)
            v = logf(fmaxf(cB[gi*S + gj], 1e-6f));
        sLog[li][lj] = v;
    }
    __syncthreads();

    // Phase B: cell fields (identical expression trees; logf inputs from sLog)
    {   float f[8];
        cellfield8_lds(cB, uB, bB, sLog, ty+1, tx+1, i0 + ty, j0 + tx, f);
        #pragma unroll
        for (int q = 0; q < 8; ++q) sF[q][ty][tx] = f[q];
    }
    if (threadIdx.x < 16 && i0 + TS < S) {
        float f[8];
        cellfield8_lds(cB, uB, bB, sLog, TS+1, (int)threadIdx.x + 1,
                       i0 + TS, j0 + threadIdx.x, f);
        #pragma unroll
        for (int q = 0; q < 8; ++q) sF[q][TS][threadIdx.x] = f[q];
    }
    if (threadIdx.x >= 64 && threadIdx.x < 80 && j0 + TS < S) {
        int k = threadIdx.x - 64;
        float f[8];
        cellfield8_lds(cB, uB, bB, sLog, k+1, TS+1, i0 + k, j0 + TS, f);
        #pragma unroll
        for (int q = 0; q < 8; ++q) sF[q][k][TS] = f[q];
    }
    __syncthreads();

    int ci = i0 + ty, cj = j0 + tx;
    int rem = ci * S + cj;
    float lap0 = sF[0][ty][tx], rho0 = sF[1][ty][tx];
    float sx0  = sF[2][ty][tx], sy0  = sF[3][ty][tx];
    float c0   = sF[4][ty][tx], u0   = sF[5][ty][tx];
    float bb0  = sF[6][ty][tx], bw0  = sF[7][ty][tx];
    float rb0, nx0, ny0; geom(ci, cj, rb0, nx0, ny0);

    if (ci < S-1) {
        float lap1 = sF[0][ty+1][tx], rho1 = sF[1][ty+1][tx], sx1 = sF[2][ty+1][tx];
        float c1 = sF[4][ty+1][tx], u1 = sF[5][ty+1][tx];
        float bb1 = sF[6][ty+1][tx], bw1 = sF[7][ty+1][tx];
        float cx = 2.f * c1 * c0 / (c1 + c0 + 1e-6f);
        cxP[(b << 18) + rem] = cx;
        float t = 0.f;
        if (cj > 0 && cj < S-1) {
            float gux = (u1 - u0) * kINVH;
            float lgx = (lap1 - lap0) * kINVH;
            float rb1, nx1, ny1; geom(ci+1, cj, rb1, nx1, ny1);
            float abb  = 0.5f * (bb1 + bb0);
            float arho = 0.5f * (rho1 + rho0);
            float asx  = 0.5f * (sx1 + sx0);
            float arb  = 0.5f * (rb1 + rb0);
            float abx  = 0.5f * (bw1 * nx1 + bw0 * nx0);
            t = abb * kH2 * cx * lgx + arho * asx * cx * gux + arb * abx * cx * gux;
        }
        taux[b * NFACE + rem] = t;
    }
    if (cj < S-1) {
        float lap1 = sF[0][ty][tx+1], rho1 = sF[1][ty][tx+1], sy1 = sF[3][ty][tx+1];
        float c1 = sF[4][ty][tx+1], u1 = sF[5][ty][tx+1];
        float bb1 = sF[6][ty][tx+1], bw1 = sF[7][ty][tx+1];
        float cy = 2.f * c1 * c0 / (c1 + c0 + 1e-6f);
        cyP[(b << 18) + rem] = cy;
        float t = 0.f;
        if (ci > 0 && ci < S-1) {
            float guy = (u1 - u0) * kINVH;
            float lgy = (lap1 - lap0) * kINVH;
            float rb1, nx1, ny1; geom(ci, cj+1, rb1, nx1, ny1);
            float abb  = 0.5f * (bb1 + bb0);
            float arho = 0.5f * (rho1 + rho0);
            float asy  = 0.5f * (sy1 + sy0);
            float arb  = 0.5f * (rb1 + rb0);
            float aby  = 0.5f * (bw1 * ny1 + bw0 * ny0);
            t = abb * kH2 * cy * lgy + arho * asy * cy * guy + arb * aby * cy * guy;
        }
        tauyP[(b << 18) + rem] = t;
    }
}

// ---------- helpers ---------------------------------------------------------------
__device__ __forceinline__ void load8(const float* __restrict__ src, float (&v)[8]) {
    float4 a = *(const float4*)(src);
    float4 c = *(const float4*)(src + 4);
    v[0]=a.x; v[1]=a.y; v[2]=a.z; v[3]=a.w; v[4]=c.x; v[5]=c.y; v[6]=c.z; v[7]=c.w;
}
__device__ __forceinline__ void store8(float* __restrict__ dst, const float (&v)[8]) {
    float4 a, c;
    a.x=v[0]; a.y=v[1]; a.z=v[2]; a.w=v[3];
    c.x=v[4]; c.y=v[5]; c.z=v[6]; c.w=v[7];
    *(float4*)(dst) = a;
    *(float4*)(dst + 4) = c;
}
// LDS row accessors, transposed layout (2 lanes/bank = conflict-free).
__device__ __forceinline__ void lds_pub(float* sr, int lane, const float (&v)[8]) {
    #pragma unroll
    for (int m = 0; m < 8; ++m) sr[m*64 + lane] = v[m];
}
__device__ __forceinline__ void lds_row(const float* sr, int lane, float (&v)[8]) {
    #pragma unroll
    for (int m = 0; m < 8; ++m) v[m] = sr[m*64 + lane];
}

// ---------- coherent edge-row exchange (R4/R8-proven path) -------------------------
// Transposed layout: element (lane, m) of a 512-float row at [m*64 + lane].
// Relaxed agent-scope scalar atomics: per-access coherent (bypass to L3),
// no fences/flushes; one wave op = 64 consecutive dwords = full sector coverage.
__device__ __forceinline__ void coh_st_row(float* rowbuf, int lane, const float (&v)[8]) {
    #pragma unroll
    for (int m = 0; m < 8; ++m)
        __hip_atomic_store(rowbuf + m*64 + lane, v[m],
                           __ATOMIC_RELAXED, __HIP_MEMORY_SCOPE_AGENT);
}
__device__ __forceinline__ void coh_ld_row(const float* rowbuf, int lane, float (&v)[8]) {
    #pragma unroll
    for (int m = 0; m < 8; ++m)
        v[m] = __hip_atomic_load(rowbuf + m*64 + lane,
                                 __ATOMIC_RELAXED, __HIP_MEMORY_SCOPE_AGENT);
}

// ---------- per-batch grid barrier (64 blocks) — R8-proven EXACTLY -----------------
// R9 lesson: spread arrivals (8 ctrs, 8 pollers) regressed. R11 lesson: fewer
// barriers with longer serial L3 chains regressed. Single counter, one poller.
__device__ __forceinline__ void gbar(unsigned* ctr, unsigned tgt) {
    __syncthreads();                       // drains vmcnt -> stores L3-visible
    if (threadIdx.x == 0) {
        __hip_atomic_fetch_add(ctr, 1u, __ATOMIC_RELAXED, __HIP_MEMORY_SCOPE_AGENT);
        long g = 0;
        while (__hip_atomic_load(ctr, __ATOMIC_RELAXED, __HIP_MEMORY_SCOPE_AGENT) < tgt) {
            __builtin_amdgcn_s_sleep(2);
            if (++g > (1L << 26)) break;
        }
    }
    __syncthreads();
}

// A(p) for this thread's 8 cells; nN/nS gathered by caller (LDS or coherent).
// Expression tree identical to verified k_iter -> bit-identical values.
__device__ __forceinline__ void apply_stencil2(
        bool rowInt, int j0, const float (&pv)[8],
        const float (&nN)[8], const float (&nS)[8],
        const float (&cxN)[8], const float (&cxS)[8],
        const float (&cyE)[8], float cyW0, float (&apv)[8]) {
    float pW = __shfl_up(pv[7], 1);   // lane l-1's east cell = my west neighbor
    float pE = __shfl_down(pv[0], 1);
    #pragma unroll
    for (int m = 0; m < 8; ++m) {
        int j = j0 + m;
        if (rowInt && j >= 1 && j <= S-2) {
            float pe  = (m < 7) ? pv[m+1] : pE;
            float pw  = (m > 0) ? pv[m-1] : pW;
            float cyw = (m > 0) ? cyE[m-1] : cyW0;
            float qxp = cxN[m] * ((nN[m] - pv[m]) * kINVH);
            float qxm = cxS[m] * ((pv[m] - nS[m]) * kINVH);
            float qyp = cyE[m] * ((pe - pv[m]) * kINVH);
            float qym = cyw   * ((pv[m] - pw) * kINVH);
            apv[m] = -((qxp - qxm) * kINVH + (qyp - qym) * kINVH);
        } else {
            apv[m] = pv[m];           // Dirichlet (boundary value is 0)
        }
    }
}

// ====== K_CG: R8 champion VERBATIM (160us, bit-exact, deterministic). =============
// 512 blocks x 512 thr (8 waves = 8-row strip; 64 strips/batch; 2 blocks/CU).
// Rows exchange within a block via LDS; only strip-edge rows cross blocks
// (transposed coherent buffers). x,r,p,ap,cx,cy live in REGISTERS for all 20
// iterations. 2 gbar/iteration — empirically optimal (R9/R11 alternatives lost).
__global__ __launch_bounds__(512, 4) void k_cg(
        const float* __restrict__ taux, const float* __restrict__ tauy,
        const float* __restrict__ cxP,  const float* __restrict__ cyP,
        const float* __restrict__ u,    float* __restrict__ out,
        float* __restrict__ prow, double* __restrict__ dots, unsigned* bar) {
    __shared__ double red[32];            // [0..3] scalar bcast; [8..31] partials
    __shared__ float srow[8][512];        // transposed p rows of this block's strip

    const int tid  = threadIdx.x;
    const int lane = tid & 63;
    const int w    = tid >> 6;            // 0..7
    const int bid  = blockIdx.x;
    const int b    = bid & 7;             // batch (XCD-local heuristic only)
    const int g    = bid >> 3;            // strip 0..63 within batch
    const int i    = (g << 3) + w;        // wave = row
    const int j0   = lane << 3;           // 8 cells per lane
    const bool rowInt = (i >= 1 && i <= S-2);
    const int base = (b << 18) + (i << 9) + j0;

    float* pubRow = prow + ((size_t)((bid << 1) | (w == 7 ? 1 : 0)) << 9);
    const bool pubEdge = (w == 0 && g > 0) || (w == 7 && g < 63);
    const float* haloS = prow + ((size_t)(((bid - 8) << 1) | 1) << 9);
    const float* haloN = prow + ((size_t)(((bid + 8) << 1) | 0) << 9);
    unsigned* ctr  = bar + (b << 4);      // 64B-padded counter per batch
    double* dslot  = dots + ((size_t)((b << 6) | g) << 2);   // [8][64][4]
    unsigned ph = 0;

    // ---- persistent coefficient registers (loaded once, normal cached reads) ----
    float cxN[8], cxS[8], cyE[8];
    float cyW0 = 0.f;
    #pragma unroll
    for (int m = 0; m < 8; ++m) { cxN[m] = 0.f; cxS[m] = 0.f; cyE[m] = 0.f; }
    if (rowInt) {
        const float* cxr = cxP + base;    // face-row i (north), i-1 (south)
        const float* cyr = cyP + base;
        load8(cxr,     cxN);
        load8(cxr - S, cxS);
        load8(cyr,     cyE);
        if (j0 > 0) cyW0 = cyr[-1];
    }

    // ---- persistent CG state ----
    float x[8], r[8], p[8], ap[8];
    #pragma unroll
    for (int m = 0; m < 8; ++m) { x[m]=0.f; r[m]=0.f; p[m]=0.f; ap[m]=0.f; }

    // ---- phase 0: rhs = div(tau); p0 = r0 = rhs (zb'ed); x = 0 ----
    if (rowInt) {
        const float* txr = taux + b * NFACE + (i << 9) + j0;
        const float* tyr = tauy + base;
        float tx0[8], txm[8], ty0[8];
        load8(txr,     tx0);
        load8(txr - S, txm);
        load8(tyr,     ty0);
        float tyW = __shfl_up(ty0[7], 1);
        #pragma unroll
        for (int m = 0; m < 8; ++m) {
            int j = j0 + m;
            if (j >= 1 && j <= S-2) {
                float tw = (m > 0) ? ty0[m-1] : tyW;
                r[m] = (tx0[m] - txm[m]) * kINVH + (ty0[m] - tw) * kINVH;
            }
            p[m] = r[m];
        }
    }
    lds_pub(srow[w], lane, p);
    if (pubEdge) coh_st_row(pubRow, lane, p);
    ++ph; gbar(ctr, ph << 6);             // A0: p0 visible batch-wide

    // ---- ap0 = A(p0); dots {pap, rap=pap, apap, rr} ----
    {
        float nN[8], nS[8];
        #pragma unroll
        for (int m = 0; m < 8; ++m) { nN[m] = 0.f; nS[m] = 0.f; }
        if (rowInt) {
            if (w == 0) coh_ld_row(haloS, lane, nS);
            else        lds_row(srow[w-1], lane, nS);
            if (w == 7) coh_ld_row(haloN, lane, nN);
            else        lds_row(srow[w+1], lane, nN);
        }
        apply_stencil2(rowInt, j0, p, nN, nS, cxN, cxS, cyE, cyW0, ap);
        double d0 = 0.0, d2 = 0.0, d3 = 0.0;
        #pragma unroll
        for (int m = 0; m < 8; ++m) {
            d0 += (double)p[m]  * (double)ap[m];
            d2 += (double)ap[m] * (double)ap[m];
            d3 += (double)r[m]  * (double)r[m];
        }
        #pragma unroll
        for (int off = 32; off > 0; off >>= 1) {
            d0 += __shfl_down(d0, off, 64);
            d2 += __shfl_down(d2, off, 64);
            d3 += __shfl_down(d3, off, 64);
        }
        if (lane == 0) { red[8+w] = d0; red[16+w] = d2; red[24+w] = d3; }
        __syncthreads();
        if (tid == 0) {
            double t0=0, t2=0, t3=0;
            #pragma unroll
            for (int q = 0; q < 8; ++q) { t0 += red[8+q]; t2 += red[16+q]; t3 += red[24+q]; }
            __hip_atomic_store(dslot+0, t0, __ATOMIC_RELAXED, __HIP_MEMORY_SCOPE_AGENT);
            __hip_atomic_store(dslot+1, t0, __ATOMIC_RELAXED, __HIP_MEMORY_SCOPE_AGENT);
            __hip_atomic_store(dslot+2, t2, __ATOMIC_RELAXED, __HIP_MEMORY_SCOPE_AGENT);
            __hip_atomic_store(dslot+3, t3, __ATOMIC_RELAXED, __HIP_MEMORY_SCOPE_AGENT);
        }
    }
    ++ph; gbar(ctr, ph << 6);             // B0: partials visible

    double rnCur = 0.0;
    for (int it = 1; it < CG_ITERS; ++it) {
        // ---- scalars: wave 0 reduces previous round's 64 partials ----
        if (w == 0) {
            const double* dr = dots + ((size_t)((b << 6) | lane) << 2);
            double s0 = __hip_atomic_load(dr+0, __ATOMIC_RELAXED, __HIP_MEMORY_SCOPE_AGENT);
            double s1 = __hip_atomic_load(dr+1, __ATOMIC_RELAXED, __HIP_MEMORY_SCOPE_AGENT);
            double s2 = __hip_atomic_load(dr+2, __ATOMIC_RELAXED, __HIP_MEMORY_SCOPE_AGENT);
            double s3 = (it == 1)
                ? __hip_atomic_load(dr+3, __ATOMIC_RELAXED, __HIP_MEMORY_SCOPE_AGENT) : 0.0;
            #pragma unroll
            for (int off = 32; off > 0; off >>= 1) {
                s0 += __shfl_down(s0, off, 64);
                s1 += __shfl_down(s1, off, 64);
                s2 += __shfl_down(s2, off, 64);
                s3 += __shfl_down(s3, off, 64);
            }
            if (lane == 0) { red[0]=s0; red[1]=s1; red[2]=s2; red[3]=s3; }
        }
        __syncthreads();
        double pap    = red[0];
        double rap    = red[1];
        double apap   = red[2];
        double rnPrev = (it == 1) ? red[3] : rnCur;
        float alphaF = (float)(rnPrev / fmax(pap, 1e-6));
        double aD = (double)alphaF;
        rnCur = rnPrev - 2.0 * aD * rap + aD * aD * apap;
        float betaF = (float)(rnCur / fmax(rnPrev, 1e-6));

        // ---- vector updates (all in registers) ----
        #pragma unroll
        for (int m = 0; m < 8; ++m) {
            x[m] += alphaF * p[m];
            r[m]  = r[m] - alphaF * ap[m];
            p[m]  = r[m] + betaF * p[m];
        }
        lds_pub(srow[w], lane, p);        // srow reads of prev round done pre-gbar B
        if (pubEdge) coh_st_row(pubRow, lane, p);
        ++ph; gbar(ctr, ph << 6);         // A: new p visible

        // ---- ap = A(p); dots {pap, rap, apap} ----
        float nN[8], nS[8];
        #pragma unroll
        for (int m = 0; m < 8; ++m) { nN[m] = 0.f; nS[m] = 0.f; }
        if (rowInt) {
            if (w == 0) coh_ld_row(haloS, lane, nS);
            else        lds_row(srow[w-1], lane, nS);
            if (w == 7) coh_ld_row(haloN, lane, nN);
            else        lds_row(srow[w+1], lane, nN);
        }
        apply_stencil2(rowInt, j0, p, nN, nS, cxN, cxS, cyE, cyW0, ap);
        double d0 = 0.0, d1 = 0.0, d2 = 0.0;
        #pragma unroll
        for (int m = 0; m < 8; ++m) {
            d0 += (double)p[m]  * (double)ap[m];
            d1 += (double)r[m]  * (double)ap[m];
            d2 += (double)ap[m] * (double)ap[m];
        }
        #pragma unroll
        for (int off = 32; off > 0; off >>= 1) {
            d0 += __shfl_down(d0, off, 64);
            d1 += __shfl_down(d1, off, 64);
            d2 += __shfl_down(d2, off, 64);
        }
        if (lane == 0) { red[8+w] = d0; red[16+w] = d1; red[24+w] = d2; }
        __syncthreads();
        if (tid == 0) {
            double t0=0, t1=0, t2=0;
            #pragma unroll
            for (int q = 0; q < 8; ++q) { t0 += red[8+q]; t1 += red[16+q]; t2 += red[24+q]; }
            __hip_atomic_store(dslot+0, t0, __ATOMIC_RELAXED, __HIP_MEMORY_SCOPE_AGENT);
            __hip_atomic_store(dslot+1, t1, __ATOMIC_RELAXED, __HIP_MEMORY_SCOPE_AGENT);
            __hip_atomic_store(dslot+2, t2, __ATOMIC_RELAXED, __HIP_MEMORY_SCOPE_AGENT);
        }
        ++ph; gbar(ctr, ph << 6);         // B: partials visible
    }

    // ---- finale: alpha_19 = rn_19 / pap_19; out = zb(u + x + alpha*p) ----
    {
        if (w == 0) {
            const double* dr = dots + ((size_t)((b << 6) | lane) << 2);
            double s0 = __hip_atomic_load(dr+0, __ATOMIC_RELAXED, __HIP_MEMORY_SCOPE_AGENT);
            #pragma unroll
            for (int off = 32; off > 0; off >>= 1) s0 += __shfl_down(s0, off, 64);
            if (lane == 0) red[0] = s0;
        }
        __syncthreads();
        double pap = red[0];
        float alphaF = (float)(rnCur / fmax(pap, 1e-6));
        float o[8];
        #pragma unroll
        for (int m = 0; m < 8; ++m) o[m] = 0.f;
        if (rowInt) {
            float uu[8];
            load8(u + base, uu);
            #pragma unroll
            for (int m = 0; m < 8; ++m) {
                int j = j0 + m;
                if (j >= 1 && j <= S-2) o[m] = uu[m] + x[m] + alphaF * p[m];
            }
        }
        store8(out + base, o);
    }
}

extern "C" void kernel_launch(void* const* d_in, const int* in_sizes, int n_in,
                              void* d_out, int out_size, void* d_ws, size_t ws_size,
                              hipStream_t stream) {
    const float* coeff = (const float*)d_in[0];
    const float* u     = (const float*)d_in[1];
    const float* beta  = (const float*)d_in[2];
    float* out = (float*)d_out;

    float* ws    = (float*)d_ws;
    float* tauxB = ws;                    // NTOT (b-stride NFACE inside)
    float* tauyB = ws + (size_t)NTOT;
    float* cxB   = ws + 2*(size_t)NTOT;
    float* cyB   = ws + 3*(size_t)NTOT;
    float* prow  = ws + 4*(size_t)NTOT;   // [512 blocks][2 edges][512] floats
    double* dots = (double*)(prow + (size_t)NBLK3*2*512);   // [8][64][4] doubles
    unsigned* bar = (unsigned*)(dots + 8*64*4);             // 8 padded counters

    // barrier counters must start at 0 (monotonic within one launch)
    (void)hipMemsetAsync(bar, 0, 4096, stream);

    k_setup<<<8192, dim3(256), 0, stream>>>(coeff, u, beta, tauxB, tauyB, cxB, cyB);
    k_cg<<<NBLK3, dim3(512), 0, stream>>>(tauxB, tauyB, cxB, cyB, u, out,
                                          prow, dots, bar);
}

// Round 13
// 241.414 us; speedup vs baseline: 1.4462x; 1.1198x over previous
//
#include <hip/hip_runtime.h>
#include <math.h>

// Problem constants (match reference)
#define S     512
#define Bsz   8
#define NCELL (S*S)              // 262144 = 2^18
#define NTOT  (Bsz*NCELL)        // 2097152
#define NFACE ((S-1)*S)          // 261632
#define CG_ITERS 20
#define NBLK4 256                // persistent grid: 32 blocks/batch, 16 rows/block
#define TS    16                 // k_setup tile

__device__ __constant__ float kINVH  = 511.0f;     // 1/h
__device__ __constant__ float kINV2H = 255.5f;
__device__ __constant__ float kH2    = (float)((1.0/511.0)*(1.0/511.0));

// ---------------- geometry (replicates numpy grid_helpers bit-exactly in double) ----
__device__ __forceinline__ void geom(int i, int j, float& rhob, float& bnx, float& bny) {
    double gx = (i == S-1) ? 1.0 : (double)i * (1.0/511.0);
    double gy = (j == S-1) ? 1.0 : (double)j * (1.0/511.0);
    double v0 = gx, v1 = 1.0 - gx, v2 = gy, v3 = 1.0 - gy;
    double m = v0; int am = 0;
    if (v1 < m) { m = v1; am = 1; }   // strict '<' == np.argmin first-min-wins
    if (v2 < m) { m = v2; am = 2; }
    if (v3 < m) { m = v3; am = 3; }
    float d = (float)m;
    rhob = expf(-(d*d) / 0.0225f);
    bnx = (am == 0) ? -1.f : (am == 1) ? 1.f : 0.f;
    bny = (am == 2) ? -1.f : (am == 3) ? 1.f : 0.f;
}

// ---- per-cell fields, logf read from staged LDS tile (R12, bit-exact-verified) ----
__device__ __forceinline__ void cellfield8_lds(const float* __restrict__ c,
                                               const float* __restrict__ uu,
                                               const float* __restrict__ bb,
                                               const float (&sL)[19][20],
                                               int li, int lj,
                                               int i, int j, float* f) {
    int rem = i * S + j;
    float cc = c[rem];
    float uc = uu[rem];
    float lapv = 0.f;
    if (i > 0 && i < S-1 && j > 0 && j < S-1) {
        float un = uu[rem + S], us = uu[rem - S];
        float ue = uu[rem + 1], uw = uu[rem - 1];
        lapv = ((un - uc)*kINVH - (uc - us)*kINVH)*kINVH
             + ((ue - uc)*kINVH - (uc - uw)*kINVH)*kINVH;
    }
    float lc = sL[li][lj];
    float glx, gly;
    if (i == 0)        { glx = (sL[li+1][lj] - lc) * kINVH; }
    else if (i == S-1) { glx = (lc - sL[li-1][lj]) * kINVH; }
    else               { glx = (sL[li+1][lj] - sL[li-1][lj]) * kINV2H; }
    if (j == 0)        { gly = (sL[li][lj+1] - lc) * kINVH; }
    else if (j == S-1) { gly = (lc - sL[li][lj-1]) * kINVH; }
    else               { gly = (sL[li][lj+1] - sL[li][lj-1]) * kINV2H; }
    float eta  = sqrtf(glx*glx + gly*gly + 1e-6f);
    float rhov = 1.f / (1.f + expf(-10.f * (eta - 0.5f)));
    float nhx = glx / eta, nhy = gly / eta;
    float4 b4 = ((const float4*)bb)[rem];
    f[0] = lapv; f[1] = rhov;
    f[2] = b4.y * nhx - b4.z * nhy;
    f[3] = b4.y * nhy + b4.z * nhx;
    f[4] = cc; f[5] = uc; f[6] = b4.x; f[7] = b4.w;
}

// ========== K_SETUP: R12 version verbatim (absmax-proven) ==========================
__global__ __launch_bounds__(256) void k_setup(
        const float* __restrict__ coeff, const float* __restrict__ u,
        const float* __restrict__ beta,
        float* __restrict__ taux, float* __restrict__ tauyP,
        float* __restrict__ cxP, float* __restrict__ cyP) {
    __shared__ float sF[8][TS+1][TS+8];
    __shared__ float sLog[19][20];
    int b  = blockIdx.x >> 10;
    int tl = blockIdx.x & 1023;
    int i0 = (tl >> 5) << 4;
    int j0 = (tl & 31) << 4;
    int tx = threadIdx.x & 15, ty = threadIdx.x >> 4;
    const float* cB = coeff + (b << 18);
    const float* uB = u     + (b << 18);
    const float* bB = beta  + ((size_t)b << 20);

    for (int t = threadIdx.x; t < 19*19; t += 256) {
        int li = t / 19, lj = t % 19;
        int gi = i0 - 1 + li, gj = j0 - 1 + lj;
        float v = 0.f;
        if (gi >= 0 && gi < S && gj >= 0 && gj < S)
            v = logf(fmaxf(cB[gi*S + gj], 1e-6f));
        sLog[li][lj] = v;
    }
    __syncthreads();

    {   float f[8];
        cellfield8_lds(cB, uB, bB, sLog, ty+1, tx+1, i0 + ty, j0 + tx, f);
        #pragma unroll
        for (int q = 0; q < 8; ++q) sF[q][ty][tx] = f[q];
    }
    if (threadIdx.x < 16 && i0 + TS < S) {
        float f[8];
        cellfield8_lds(cB, uB, bB, sLog, TS+1, (int)threadIdx.x + 1,
                       i0 + TS, j0 + threadIdx.x, f);
        #pragma unroll
        for (int q = 0; q < 8; ++q) sF[q][TS][threadIdx.x] = f[q];
    }
    if (threadIdx.x >= 64 && threadIdx.x < 80 && j0 + TS < S) {
        int k = threadIdx.x - 64;
        float f[8];
        cellfield8_lds(cB, uB, bB, sLog, k+1, TS+1, i0 + k, j0 + TS, f);
        #pragma unroll
        for (int q = 0; q < 8; ++q) sF[q][k][TS] = f[q];
    }
    __syncthreads();

    int ci = i0 + ty, cj = j0 + tx;
    int rem = ci * S + cj;
    float lap0 = sF[0][ty][tx], rho0 = sF[1][ty][tx];
    float sx0  = sF[2][ty][tx], sy0  = sF[3][ty][tx];
    float c0   = sF[4][ty][tx], u0   = sF[5][ty][tx];
    float bb0  = sF[6][ty][tx], bw0  = sF[7][ty][tx];
    float rb0, nx0, ny0; geom(ci, cj, rb0, nx0, ny0);

    if (ci < S-1) {
        float lap1 = sF[0][ty+1][tx], rho1 = sF[1][ty+1][tx], sx1 = sF[2][ty+1][tx];
        float c1 = sF[4][ty+1][tx], u1 = sF[5][ty+1][tx];
        float bb1 = sF[6][ty+1][tx], bw1 = sF[7][ty+1][tx];
        float cx = 2.f * c1 * c0 / (c1 + c0 + 1e-6f);
        cxP[(b << 18) + rem] = cx;
        float t = 0.f;
        if (cj > 0 && cj < S-1) {
            float gux = (u1 - u0) * kINVH;
            float lgx = (lap1 - lap0) * kINVH;
            float rb1, nx1, ny1; geom(ci+1, cj, rb1, nx1, ny1);
            float abb  = 0.5f * (bb1 + bb0);
            float arho = 0.5f * (rho1 + rho0);
            float asx  = 0.5f * (sx1 + sx0);
            float arb  = 0.5f * (rb1 + rb0);
            float abx  = 0.5f * (bw1 * nx1 + bw0 * nx0);
            t = abb * kH2 * cx * lgx + arho * asx * cx * gux + arb * abx * cx * gux;
        }
        taux[b * NFACE + rem] = t;
    }
    if (cj < S-1) {
        float lap1 = sF[0][ty][tx+1], rho1 = sF[1][ty][tx+1], sy1 = sF[3][ty][tx+1];
        float c1 = sF[4][ty][tx+1], u1 = sF[5][ty][tx+1];
        float bb1 = sF[6][ty][tx+1], bw1 = sF[7][ty][tx+1];
        float cy = 2.f * c1 * c0 / (c1 + c0 + 1e-6f);
        cyP[(b << 18) + rem] = cy;
        float t = 0.f;
        if (ci > 0 && ci < S-1) {
            float guy = (u1 - u0) * kINVH;
            float lgy = (lap1 - lap0) * kINVH;
            float rb1, nx1, ny1; geom(ci, cj+1, rb1, nx1, ny1);
            float abb  = 0.5f * (bb1 + bb0);
            float arho = 0.5f * (rho1 + rho0);
            float asy  = 0.5f * (sy1 + sy0);
            float arb  = 0.5f * (rb1 + rb0);
            float aby  = 0.5f * (bw1 * ny1 + bw0 * ny0);
            t = abb * kH2 * cy * lgy + arho * asy * cy * guy + arb * aby * cy * guy;
        }
        tauyP[(b << 18) + rem] = t;
    }
}

// ---------- helpers ---------------------------------------------------------------
__device__ __forceinline__ void load8(const float* __restrict__ src, float (&v)[8]) {
    float4 a = *(const float4*)(src);
    float4 c = *(const float4*)(src + 4);
    v[0]=a.x; v[1]=a.y; v[2]=a.z; v[3]=a.w; v[4]=c.x; v[5]=c.y; v[6]=c.z; v[7]=c.w;
}
__device__ __forceinline__ void store8(float* __restrict__ dst, const float (&v)[8]) {
    float4 a, c;
    a.x=v[0]; a.y=v[1]; a.z=v[2]; a.w=v[3];
    c.x=v[4]; c.y=v[5]; c.z=v[6]; c.w=v[7];
    *(float4*)(dst) = a;
    *(float4*)(dst + 4) = c;
}
// LDS row accessors, transposed layout (2 lanes/bank = conflict-free).
__device__ __forceinline__ void lds_pub(float* sr, int lane, const float (&v)[8]) {
    #pragma unroll
    for (int m = 0; m < 8; ++m) sr[m*64 + lane] = v[m];
}
__device__ __forceinline__ void lds_row(const float* sr, int lane, float (&v)[8]) {
    #pragma unroll
    for (int m = 0; m < 8; ++m) v[m] = sr[m*64 + lane];
}

// ---------- coherent edge-row exchange (R4/R8-proven path) -------------------------
__device__ __forceinline__ void coh_st_row(float* rowbuf, int lane, const float (&v)[8]) {
    #pragma unroll
    for (int m = 0; m < 8; ++m)
        __hip_atomic_store(rowbuf + m*64 + lane, v[m],
                           __ATOMIC_RELAXED, __HIP_MEMORY_SCOPE_AGENT);
}
__device__ __forceinline__ void coh_ld_row(const float* rowbuf, int lane, float (&v)[8]) {
    #pragma unroll
    for (int m = 0; m < 8; ++m)
        v[m] = __hip_atomic_load(rowbuf + m*64 + lane,
                                 __ATOMIC_RELAXED, __HIP_MEMORY_SCOPE_AGENT);
}

// ---------- per-batch grid barrier (32 blocks) — R8-proven protocol ----------------
// Single counter, one poller per block. Participants halved again (64 -> 32).
__device__ __forceinline__ void gbar(unsigned* ctr, unsigned tgt) {
    __syncthreads();                       // drains vmcnt -> stores L3-visible
    if (threadIdx.x == 0) {
        __hip_atomic_fetch_add(ctr, 1u, __ATOMIC_RELAXED, __HIP_MEMORY_SCOPE_AGENT);
        long g = 0;
        while (__hip_atomic_load(ctr, __ATOMIC_RELAXED, __HIP_MEMORY_SCOPE_AGENT) < tgt) {
            __builtin_amdgcn_s_sleep(2);
            if (++g > (1L << 26)) break;
        }
    }
    __syncthreads();
}

// A(p): expression tree identical to verified k_iter -> bit-identical values.
__device__ __forceinline__ void apply_stencil2(
        bool rowInt, int j0, const float (&pv)[8],
        const float (&nN)[8], const float (&nS)[8],
        const float (&cxN)[8], const float (&cxS)[8],
        const float (&cyE)[8], float cyW0, float (&apv)[8]) {
    float pW = __shfl_up(pv[7], 1);
    float pE = __shfl_down(pv[0], 1);
    #pragma unroll
    for (int m = 0; m < 8; ++m) {
        int j = j0 + m;
        if (rowInt && j >= 1 && j <= S-2) {
            float pe  = (m < 7) ? pv[m+1] : pE;
            float pw  = (m > 0) ? pv[m-1] : pW;
            float cyw = (m > 0) ? cyE[m-1] : cyW0;
            float qxp = cxN[m] * ((nN[m] - pv[m]) * kINVH);
            float qxm = cxS[m] * ((pv[m] - nS[m]) * kINVH);
            float qyp = cyE[m] * ((pe - pv[m]) * kINVH);
            float qym = cyw   * ((pv[m] - pw) * kINVH);
            apv[m] = -((qxp - qxm) * kINVH + (qyp - qym) * kINVH);
        } else {
            apv[m] = pv[m];           // Dirichlet (boundary value is 0)
        }
    }
}

// ====== K_CG: R8 protocol, scaled to 16-row strips / 1024-thread blocks. ==========
// 256 blocks x 1024 thr = exactly 1 block/CU (16 waves). 32 strips/batch ->
// 32 barrier participants (was 64), edge traffic 1 MB/iter (was 2), dots slots
// 32 (was 64). With bid&7 batching and round-robin dispatch, each batch's sync
// domain is XCD-local. Protocol and numerics identical to R8/R12 champion.
__global__ __launch_bounds__(1024, 4) void k_cg(
        const float* __restrict__ taux, const float* __restrict__ tauy,
        const float* __restrict__ cxP,  const float* __restrict__ cyP,
        const float* __restrict__ u,    float* __restrict__ out,
        float* __restrict__ prow, double* __restrict__ dots, unsigned* bar) {
    __shared__ double red[72];            // [0..3] scalars; [8..23] [24..39] [40..55]
    __shared__ float srow[16][512];       // transposed p rows of this block's strip

    const int tid  = threadIdx.x;
    const int lane = tid & 63;
    const int w    = tid >> 6;            // 0..15
    const int bid  = blockIdx.x;
    const int b    = bid & 7;             // batch (XCD-local under round-robin)
    const int g    = bid >> 3;            // strip 0..31 within batch
    const int i    = (g << 4) + w;        // wave = row
    const int j0   = lane << 3;           // 8 cells per lane
    const bool rowInt = (i >= 1 && i <= S-2);
    const int base = (b << 18) + (i << 9) + j0;

    float* pubRow = prow + ((size_t)((bid << 1) | (w == 15 ? 1 : 0)) << 9);
    const bool pubEdge = (w == 0 && g > 0) || (w == 15 && g < 31);
    const float* haloS = prow + ((size_t)(((bid - 8) << 1) | 1) << 9);
    const float* haloN = prow + ((size_t)(((bid + 8) << 1) | 0) << 9);
    unsigned* ctr  = bar + (b << 4);      // 64B-padded counter per batch
    double* dslot  = dots + ((size_t)((b << 5) | g) << 2);   // [8][32][4]
    unsigned ph = 0;

    // ---- persistent coefficient registers ----
    float cxN[8], cxS[8], cyE[8];
    float cyW0 = 0.f;
    #pragma unroll
    for (int m = 0; m < 8; ++m) { cxN[m] = 0.f; cxS[m] = 0.f; cyE[m] = 0.f; }
    if (rowInt) {
        const float* cxr = cxP + base;
        const float* cyr = cyP + base;
        load8(cxr,     cxN);
        load8(cxr - S, cxS);
        load8(cyr,     cyE);
        if (j0 > 0) cyW0 = cyr[-1];
    }

    // ---- persistent CG state ----
    float x[8], r[8], p[8], ap[8];
    #pragma unroll
    for (int m = 0; m < 8; ++m) { x[m]=0.f; r[m]=0.f; p[m]=0.f; ap[m]=0.f; }

    // ---- phase 0: rhs = div(tau); p0 = r0 = rhs (zb'ed); x = 0 ----
    if (rowInt) {
        const float* txr = taux + b * NFACE + (i << 9) + j0;
        const float* tyr = tauy + base;
        float tx0[8], txm[8], ty0[8];
        load8(txr,     tx0);
        load8(txr - S, txm);
        load8(tyr,     ty0);
        float tyW = __shfl_up(ty0[7], 1);
        #pragma unroll
        for (int m = 0; m < 8; ++m) {
            int j = j0 + m;
            if (j >= 1 && j <= S-2) {
                float tw = (m > 0) ? ty0[m-1] : tyW;
                r[m] = (tx0[m] - txm[m]) * kINVH + (ty0[m] - tw) * kINVH;
            }
            p[m] = r[m];
        }
    }
    lds_pub(srow[w], lane, p);
    if (pubEdge) coh_st_row(pubRow, lane, p);
    ++ph; gbar(ctr, ph << 5);             // A0: p0 visible batch-wide

    // ---- ap0 = A(p0); dots {pap, rap=pap, apap, rr} ----
    {
        float nN[8], nS[8];
        #pragma unroll
        for (int m = 0; m < 8; ++m) { nN[m] = 0.f; nS[m] = 0.f; }
        if (rowInt) {
            if (w == 0)  coh_ld_row(haloS, lane, nS);
            else         lds_row(srow[w-1], lane, nS);
            if (w == 15) coh_ld_row(haloN, lane, nN);
            else         lds_row(srow[w+1], lane, nN);
        }
        apply_stencil2(rowInt, j0, p, nN, nS, cxN, cxS, cyE, cyW0, ap);
        double d0 = 0.0, d2 = 0.0, d3 = 0.0;
        #pragma unroll
        for (int m = 0; m < 8; ++m) {
            d0 += (double)p[m]  * (double)ap[m];
            d2 += (double)ap[m] * (double)ap[m];
            d3 += (double)r[m]  * (double)r[m];
        }
        #pragma unroll
        for (int off = 32; off > 0; off >>= 1) {
            d0 += __shfl_down(d0, off, 64);
            d2 += __shfl_down(d2, off, 64);
            d3 += __shfl_down(d3, off, 64);
        }
        if (lane == 0) { red[8+w] = d0; red[24+w] = d2; red[40+w] = d3; }
        __syncthreads();
        if (tid == 0) {
            double t0=0, t2=0, t3=0;
            #pragma unroll
            for (int q = 0; q < 16; ++q) { t0 += red[8+q]; t2 += red[24+q]; t3 += red[40+q]; }
            __hip_atomic_store(dslot+0, t0, __ATOMIC_RELAXED, __HIP_MEMORY_SCOPE_AGENT);
            __hip_atomic_store(dslot+1, t0, __ATOMIC_RELAXED, __HIP_MEMORY_SCOPE_AGENT);
            __hip_atomic_store(dslot+2, t2, __ATOMIC_RELAXED, __HIP_MEMORY_SCOPE_AGENT);
            __hip_atomic_store(dslot+3, t3, __ATOMIC_RELAXED, __HIP_MEMORY_SCOPE_AGENT);
        }
    }
    ++ph; gbar(ctr, ph << 5);             // B0: partials visible

    double rnCur = 0.0;
    for (int it = 1; it < CG_ITERS; ++it) {
        // ---- scalars: wave 0 (lanes 0..31) reduces previous round's 32 partials ----
        if (w == 0) {
            double s0 = 0.0, s1 = 0.0, s2 = 0.0, s3 = 0.0;
            if (lane < 32) {
                const double* dr = dots + ((size_t)((b << 5) | lane) << 2);
                s0 = __hip_atomic_load(dr+0, __ATOMIC_RELAXED, __HIP_MEMORY_SCOPE_AGENT);
                s1 = __hip_atomic_load(dr+1, __ATOMIC_RELAXED, __HIP_MEMORY_SCOPE_AGENT);
                s2 = __hip_atomic_load(dr+2, __ATOMIC_RELAXED, __HIP_MEMORY_SCOPE_AGENT);
                if (it == 1)
                    s3 = __hip_atomic_load(dr+3, __ATOMIC_RELAXED, __HIP_MEMORY_SCOPE_AGENT);
            }
            #pragma unroll
            for (int off = 32; off > 0; off >>= 1) {
                s0 += __shfl_down(s0, off, 64);
                s1 += __shfl_down(s1, off, 64);
                s2 += __shfl_down(s2, off, 64);
                s3 += __shfl_down(s3, off, 64);
            }
            if (lane == 0) { red[0]=s0; red[1]=s1; red[2]=s2; red[3]=s3; }
        }
        __syncthreads();
        double pap    = red[0];
        double rap    = red[1];
        double apap   = red[2];
        double rnPrev = (it == 1) ? red[3] : rnCur;
        float alphaF = (float)(rnPrev / fmax(pap, 1e-6));
        double aD = (double)alphaF;
        rnCur = rnPrev - 2.0 * aD * rap + aD * aD * apap;
        float betaF = (float)(rnCur / fmax(rnPrev, 1e-6));

        // ---- vector updates (all in registers) ----
        #pragma unroll
        for (int m = 0; m < 8; ++m) {
            x[m] += alphaF * p[m];
            r[m]  = r[m] - alphaF * ap[m];
            p[m]  = r[m] + betaF * p[m];
        }
        lds_pub(srow[w], lane, p);        // srow reads of prev round done pre-gbar B
        if (pubEdge) coh_st_row(pubRow, lane, p);
        ++ph; gbar(ctr, ph << 5);         // A: new p visible

        // ---- ap = A(p); dots {pap, rap, apap} ----
        float nN[8], nS[8];
        #pragma unroll
        for (int m = 0; m < 8; ++m) { nN[m] = 0.f; nS[m] = 0.f; }
        if (rowInt) {
            if (w == 0)  coh_ld_row(haloS, lane, nS);
            else         lds_row(srow[w-1], lane, nS);
            if (w == 15) coh_ld_row(haloN, lane, nN);
            else         lds_row(srow[w+1], lane, nN);
        }
        apply_stencil2(rowInt, j0, p, nN, nS, cxN, cxS, cyE, cyW0, ap);
        double d0 = 0.0, d1 = 0.0, d2 = 0.0;
        #pragma unroll
        for (int m = 0; m < 8; ++m) {
            d0 += (double)p[m]  * (double)ap[m];
            d1 += (double)r[m]  * (double)ap[m];
            d2 += (double)ap[m] * (double)ap[m];
        }
        #pragma unroll
        for (int off = 32; off > 0; off >>= 1) {
            d0 += __shfl_down(d0, off, 64);
            d1 += __shfl_down(d1, off, 64);
            d2 += __shfl_down(d2, off, 64);
        }
        if (lane == 0) { red[8+w] = d0; red[24+w] = d1; red[40+w] = d2; }
        __syncthreads();
        if (tid == 0) {
            double t0=0, t1=0, t2=0;
            #pragma unroll
            for (int q = 0; q < 16; ++q) { t0 += red[8+q]; t1 += red[24+q]; t2 += red[40+q]; }
            __hip_atomic_store(dslot+0, t0, __ATOMIC_RELAXED, __HIP_MEMORY_SCOPE_AGENT);
            __hip_atomic_store(dslot+1, t1, __ATOMIC_RELAXED, __HIP_MEMORY_SCOPE_AGENT);
            __hip_atomic_store(dslot+2, t2, __ATOMIC_RELAXED, __HIP_MEMORY_SCOPE_AGENT);
        }
        ++ph; gbar(ctr, ph << 5);         // B: partials visible
    }

    // ---- finale: alpha_19 = rn_19 / pap_19; out = zb(u + x + alpha*p) ----
    {
        if (w == 0) {
            double s0 = 0.0;
            if (lane < 32) {
                const double* dr = dots + ((size_t)((b << 5) | lane) << 2);
                s0 = __hip_atomic_load(dr+0, __ATOMIC_RELAXED, __HIP_MEMORY_SCOPE_AGENT);
            }
            #pragma unroll
            for (int off = 32; off > 0; off >>= 1) s0 += __shfl_down(s0, off, 64);
            if (lane == 0) red[0] = s0;
        }
        __syncthreads();
        double pap = red[0];
        float alphaF = (float)(rnCur / fmax(pap, 1e-6));
        float o[8];
        #pragma unroll
        for (int m = 0; m < 8; ++m) o[m] = 0.f;
        if (rowInt) {
            float uu[8];
            load8(u + base, uu);
            #pragma unroll
            for (int m = 0; m < 8; ++m) {
                int j = j0 + m;
                if (j >= 1 && j <= S-2) o[m] = uu[m] + x[m] + alphaF * p[m];
            }
        }
        store8(out + base, o);
    }
}

extern "C" void kernel_launch(void* const* d_in, const int* in_sizes, int n_in,
                              void* d_out, int out_size, void* d_ws, size_t ws_size,
                              hipStream_t stream) {
    const float* coeff = (const float*)d_in[0];
    const float* u     = (const float*)d_in[1];
    const float* beta  = (const float*)d_in[2];
    float* out = (float*)d_out;

    float* ws    = (float*)d_ws;
    float* tauxB = ws;                    // NTOT (b-stride NFACE inside)
    float* tauyB = ws + (size_t)NTOT;
    float* cxB   = ws + 2*(size_t)NTOT;
    float* cyB   = ws + 3*(size_t)NTOT;
    float* prow  = ws + 4*(size_t)NTOT;   // [256 blocks][2 edges][512] floats
    double* dots = (double*)(prow + (size_t)NBLK4*2*512);   // [8][32][4] doubles
    unsigned* bar = (unsigned*)(dots + 8*32*4);             // 8 padded counters

    // barrier counters must start at 0 (monotonic within one launch)
    (void)hipMemsetAsync(bar, 0, 4096, stream);

    k_setup<<<8192, dim3(256), 0, stream>>>(coeff, u, beta, tauxB, tauyB, cxB, cyB);
    k_cg<<<NBLK4, dim3(1024), 0, stream>>>(tauxB, tauyB, cxB, cyB, u, out,
                                           prow, dots, bar);
}

// Round 14
// 239.405 us; speedup vs baseline: 1.4584x; 1.0084x over previous
//
#include <hip/hip_runtime.h>
#include <math.h>

// Problem constants (match reference)
#define S     512
#define Bsz   8
#define NCELL (S*S)              // 262144 = 2^18
#define NTOT  (Bsz*NCELL)        // 2097152
#define NFACE ((S-1)*S)          // 261632
#define CG_ITERS 20
#define NBLK4 256                // persistent grid: 32 blocks/batch, 16 rows/block
#define TS    16                 // k_setup tile

__device__ __constant__ float kINVH  = 511.0f;     // 1/h
__device__ __constant__ float kINV2H = 255.5f;
__device__ __constant__ float kH2    = (float)((1.0/511.0)*(1.0/511.0));

// ---------------- geometry (replicates numpy grid_helpers bit-exactly in double) ----
__device__ __forceinline__ void geom(int i, int j, float& rhob, float& bnx, float& bny) {
    double gx = (i == S-1) ? 1.0 : (double)i * (1.0/511.0);
    double gy = (j == S-1) ? 1.0 : (double)j * (1.0/511.0);
    double v0 = gx, v1 = 1.0 - gx, v2 = gy, v3 = 1.0 - gy;
    double m = v0; int am = 0;
    if (v1 < m) { m = v1; am = 1; }   // strict '<' == np.argmin first-min-wins
    if (v2 < m) { m = v2; am = 2; }
    if (v3 < m) { m = v3; am = 3; }
    float d = (float)m;
    rhob = expf(-(d*d) / 0.0225f);
    bnx = (am == 0) ? -1.f : (am == 1) ? 1.f : 0.f;
    bny = (am == 2) ? -1.f : (am == 3) ? 1.f : 0.f;
}

// ---- per-cell fields; expressions identical to verified pipeline (R8) -------------
__device__ __forceinline__ void cellfield8(const float* __restrict__ c,
                                           const float* __restrict__ uu,
                                           const float* __restrict__ bb,
                                           int i, int j, float* f) {
    int rem = i * S + j;
    float cc = c[rem];
    float uc = uu[rem];
    float lapv = 0.f;
    if (i > 0 && i < S-1 && j > 0 && j < S-1) {
        float un = uu[rem + S], us = uu[rem - S];
        float ue = uu[rem + 1], uw = uu[rem - 1];
        lapv = ((un - uc)*kINVH - (uc - us)*kINVH)*kINVH
             + ((ue - uc)*kINVH - (uc - uw)*kINVH)*kINVH;
    }
    float glx, gly;
    float lc = logf(fmaxf(cc, 1e-6f));
    if (i == 0)        { glx = (logf(fmaxf(c[rem+S],1e-6f)) - lc) * kINVH; }
    else if (i == S-1) { glx = (lc - logf(fmaxf(c[rem-S],1e-6f))) * kINVH; }
    else { glx = (logf(fmaxf(c[rem+S],1e-6f)) - logf(fmaxf(c[rem-S],1e-6f))) * kINV2H; }
    if (j == 0)        { gly = (logf(fmaxf(c[rem+1],1e-6f)) - lc) * kINVH; }
    else if (j == S-1) { gly = (lc - logf(fmaxf(c[rem-1],1e-6f))) * kINVH; }
    else { gly = (logf(fmaxf(c[rem+1],1e-6f)) - logf(fmaxf(c[rem-1],1e-6f))) * kINV2H; }
    float eta  = sqrtf(glx*glx + gly*gly + 1e-6f);
    float rhov = 1.f / (1.f + expf(-10.f * (eta - 0.5f)));
    float nhx = glx / eta, nhy = gly / eta;
    float4 b4 = ((const float4*)bb)[rem];
    f[0] = lapv; f[1] = rhov;
    f[2] = b4.y * nhx - b4.z * nhy;
    f[3] = b4.y * nhy + b4.z * nhx;
    f[4] = cc; f[5] = uc; f[6] = b4.x; f[7] = b4.w;
}

// ========== K_SETUP: R8 version VERBATIM (inline geom + inline logf; proven 42us) ==
__global__ __launch_bounds__(256) void k_setup(
        const float* __restrict__ coeff, const float* __restrict__ u,
        const float* __restrict__ beta,
        float* __restrict__ taux, float* __restrict__ tauyP,
        float* __restrict__ cxP, float* __restrict__ cyP) {
    __shared__ float sF[8][TS+1][TS+8];
    int b  = blockIdx.x >> 10;
    int tl = blockIdx.x & 1023;
    int i0 = (tl >> 5) << 4;
    int j0 = (tl & 31) << 4;
    int tx = threadIdx.x & 15, ty = threadIdx.x >> 4;
    const float* cB = coeff + (b << 18);
    const float* uB = u     + (b << 18);
    const float* bB = beta  + ((size_t)b << 20);

    {   float f[8];
        cellfield8(cB, uB, bB, i0 + ty, j0 + tx, f);
        #pragma unroll
        for (int q = 0; q < 8; ++q) sF[q][ty][tx] = f[q];
    }
    if (threadIdx.x < 16 && i0 + TS < S) {
        float f[8];
        cellfield8(cB, uB, bB, i0 + TS, j0 + threadIdx.x, f);
        #pragma unroll
        for (int q = 0; q < 8; ++q) sF[q][TS][threadIdx.x] = f[q];
    }
    if (threadIdx.x >= 64 && threadIdx.x < 80 && j0 + TS < S) {
        int k = threadIdx.x - 64;
        float f[8];
        cellfield8(cB, uB, bB, i0 + k, j0 + TS, f);
        #pragma unroll
        for (int q = 0; q < 8; ++q) sF[q][k][TS] = f[q];
    }
    __syncthreads();

    int ci = i0 + ty, cj = j0 + tx;
    int rem = ci * S + cj;
    float lap0 = sF[0][ty][tx], rho0 = sF[1][ty][tx];
    float sx0  = sF[2][ty][tx], sy0  = sF[3][ty][tx];
    float c0   = sF[4][ty][tx], u0   = sF[5][ty][tx];
    float bb0  = sF[6][ty][tx], bw0  = sF[7][ty][tx];
    float rb0, nx0, ny0; geom(ci, cj, rb0, nx0, ny0);

    if (ci < S-1) {
        float lap1 = sF[0][ty+1][tx], rho1 = sF[1][ty+1][tx], sx1 = sF[2][ty+1][tx];
        float c1 = sF[4][ty+1][tx], u1 = sF[5][ty+1][tx];
        float bb1 = sF[6][ty+1][tx], bw1 = sF[7][ty+1][tx];
        float cx = 2.f * c1 * c0 / (c1 + c0 + 1e-6f);
        cxP[(b << 18) + rem] = cx;
        float t = 0.f;
        if (cj > 0 && cj < S-1) {
            float gux = (u1 - u0) * kINVH;
            float lgx = (lap1 - lap0) * kINVH;
            float rb1, nx1, ny1; geom(ci+1, cj, rb1, nx1, ny1);
            float abb  = 0.5f * (bb1 + bb0);
            float arho = 0.5f * (rho1 + rho0);
            float asx  = 0.5f * (sx1 + sx0);
            float arb  = 0.5f * (rb1 + rb0);
            float abx  = 0.5f * (bw1 * nx1 + bw0 * nx0);
            t = abb * kH2 * cx * lgx + arho * asx * cx * gux + arb * abx * cx * gux;
        }
        taux[b * NFACE + rem] = t;
    }
    if (cj < S-1) {
        float lap1 = sF[0][ty][tx+1], rho1 = sF[1][ty][tx+1], sy1 = sF[3][ty][tx+1];
        float c1 = sF[4][ty][tx+1], u1 = sF[5][ty][tx+1];
        float bb1 = sF[6][ty][tx+1], bw1 = sF[7][ty][tx+1];
        float cy = 2.f * c1 * c0 / (c1 + c0 + 1e-6f);
        cyP[(b << 18) + rem] = cy;
        float t = 0.f;
        if (ci > 0 && ci < S-1) {
            float guy = (u1 - u0) * kINVH;
            float lgy = (lap1 - lap0) * kINVH;
            float rb1, nx1, ny1; geom(ci, cj+1, rb1, nx1, ny1);
            float abb  = 0.5f * (bb1 + bb0);
            float arho = 0.5f * (rho1 + rho0);
            float asy  = 0.5f * (sy1 + sy0);
            float arb  = 0.5f * (rb1 + rb0);
            float aby  = 0.5f * (bw1 * ny1 + bw0 * ny0);
            t = abb * kH2 * cy * lgy + arho * asy * cy * guy + arb * aby * cy * guy;
        }
        tauyP[(b << 18) + rem] = t;
    }
}

// ---------- helpers ---------------------------------------------------------------
__device__ __forceinline__ void load8(const float* __restrict__ src, float (&v)[8]) {
    float4 a = *(const float4*)(src);
    float4 c = *(const float4*)(src + 4);
    v[0]=a.x; v[1]=a.y; v[2]=a.z; v[3]=a.w; v[4]=c.x; v[5]=c.y; v[6]=c.z; v[7]=c.w;
}
__device__ __forceinline__ void store8(float* __restrict__ dst, const float (&v)[8]) {
    float4 a, c;
    a.x=v[0]; a.y=v[1]; a.z=v[2]; a.w=v[3];
    c.x=v[4]; c.y=v[5]; c.z=v[6]; c.w=v[7];
    *(float4*)(dst) = a;
    *(float4*)(dst + 4) = c;
}
// LDS row accessors, transposed layout (2 lanes/bank = conflict-free).
__device__ __forceinline__ void lds_pub(float* sr, int lane, const float (&v)[8]) {
    #pragma unroll
    for (int m = 0; m < 8; ++m) sr[m*64 + lane] = v[m];
}
__device__ __forceinline__ void lds_row(const float* sr, int lane, float (&v)[8]) {
    #pragma unroll
    for (int m = 0; m < 8; ++m) v[m] = sr[m*64 + lane];
}

// ---------- coherent edge-row exchange (R4/R8-proven path) -------------------------
__device__ __forceinline__ void coh_st_row(float* rowbuf, int lane, const float (&v)[8]) {
    #pragma unroll
    for (int m = 0; m < 8; ++m)
        __hip_atomic_store(rowbuf + m*64 + lane, v[m],
                           __ATOMIC_RELAXED, __HIP_MEMORY_SCOPE_AGENT);
}
__device__ __forceinline__ void coh_ld_row(const float* rowbuf, int lane, float (&v)[8]) {
    #pragma unroll
    for (int m = 0; m < 8; ++m)
        v[m] = __hip_atomic_load(rowbuf + m*64 + lane,
                                 __ATOMIC_RELAXED, __HIP_MEMORY_SCOPE_AGENT);
}

// ---------- per-batch grid barrier (32 blocks) — R8-proven protocol ----------------
__device__ __forceinline__ void gbar(unsigned* ctr, unsigned tgt) {
    __syncthreads();                       // drains vmcnt -> stores L3-visible
    if (threadIdx.x == 0) {
        __hip_atomic_fetch_add(ctr, 1u, __ATOMIC_RELAXED, __HIP_MEMORY_SCOPE_AGENT);
        long g = 0;
        while (__hip_atomic_load(ctr, __ATOMIC_RELAXED, __HIP_MEMORY_SCOPE_AGENT) < tgt) {
            __builtin_amdgcn_s_sleep(2);
            if (++g > (1L << 26)) break;
        }
    }
    __syncthreads();
}

// A(p): expression tree identical to verified k_iter -> bit-identical values.
__device__ __forceinline__ void apply_stencil2(
        bool rowInt, int j0, const float (&pv)[8],
        const float (&nN)[8], const float (&nS)[8],
        const float (&cxN)[8], const float (&cxS)[8],
        const float (&cyE)[8], float cyW0, float (&apv)[8]) {
    float pW = __shfl_up(pv[7], 1);
    float pE = __shfl_down(pv[0], 1);
    #pragma unroll
    for (int m = 0; m < 8; ++m) {
        int j = j0 + m;
        if (rowInt && j >= 1 && j <= S-2) {
            float pe  = (m < 7) ? pv[m+1] : pE;
            float pw  = (m > 0) ? pv[m-1] : pW;
            float cyw = (m > 0) ? cyE[m-1] : cyW0;
            float qxp = cxN[m] * ((nN[m] - pv[m]) * kINVH);
            float qxm = cxS[m] * ((pv[m] - nS[m]) * kINVH);
            float qyp = cyE[m] * ((pe - pv[m]) * kINVH);
            float qym = cyw   * ((pv[m] - pw) * kINVH);
            apv[m] = -((qxp - qxm) * kINVH + (qyp - qym) * kINVH);
        } else {
            apv[m] = pv[m];           // Dirichlet (boundary value is 0)
        }
    }
}

// ====== K_CG: R13 champion VERBATIM (126us). 16-row strips / 1024-thr blocks. =====
// 256 blocks = 1 block/CU; 32 strips/batch -> 32 barrier participants; batch sync
// domain XCD-local under round-robin (perf heuristic; correctness via L3 atomics).
__global__ __launch_bounds__(1024, 4) void k_cg(
        const float* __restrict__ taux, const float* __restrict__ tauy,
        const float* __restrict__ cxP,  const float* __restrict__ cyP,
        const float* __restrict__ u,    float* __restrict__ out,
        float* __restrict__ prow, double* __restrict__ dots, unsigned* bar) {
    __shared__ double red[72];            // [0..3] scalars; [8..23] [24..39] [40..55]
    __shared__ float srow[16][512];       // transposed p rows of this block's strip

    const int tid  = threadIdx.x;
    const int lane = tid & 63;
    const int w    = tid >> 6;            // 0..15
    const int bid  = blockIdx.x;
    const int b    = bid & 7;             // batch (XCD-local under round-robin)
    const int g    = bid >> 3;            // strip 0..31 within batch
    const int i    = (g << 4) + w;        // wave = row
    const int j0   = lane << 3;           // 8 cells per lane
    const bool rowInt = (i >= 1 && i <= S-2);
    const int base = (b << 18) + (i << 9) + j0;

    float* pubRow = prow + ((size_t)((bid << 1) | (w == 15 ? 1 : 0)) << 9);
    const bool pubEdge = (w == 0 && g > 0) || (w == 15 && g < 31);
    const float* haloS = prow + ((size_t)(((bid - 8) << 1) | 1) << 9);
    const float* haloN = prow + ((size_t)(((bid + 8) << 1) | 0) << 9);
    unsigned* ctr  = bar + (b << 4);      // 64B-padded counter per batch
    double* dslot  = dots + ((size_t)((b << 5) | g) << 2);   // [8][32][4]
    unsigned ph = 0;

    // ---- persistent coefficient registers ----
    float cxN[8], cxS[8], cyE[8];
    float cyW0 = 0.f;
    #pragma unroll
    for (int m = 0; m < 8; ++m) { cxN[m] = 0.f; cxS[m] = 0.f; cyE[m] = 0.f; }
    if (rowInt) {
        const float* cxr = cxP + base;
        const float* cyr = cyP + base;
        load8(cxr,     cxN);
        load8(cxr - S, cxS);
        load8(cyr,     cyE);
        if (j0 > 0) cyW0 = cyr[-1];
    }

    // ---- persistent CG state ----
    float x[8], r[8], p[8], ap[8];
    #pragma unroll
    for (int m = 0; m < 8; ++m) { x[m]=0.f; r[m]=0.f; p[m]=0.f; ap[m]=0.f; }

    // ---- phase 0: rhs = div(tau); p0 = r0 = rhs (zb'ed); x = 0 ----
    if (rowInt) {
        const float* txr = taux + b * NFACE + (i << 9) + j0;
        const float* tyr = tauy + base;
        float tx0[8], txm[8], ty0[8];
        load8(txr,     tx0);
        load8(txr - S, txm);
        load8(tyr,     ty0);
        float tyW = __shfl_up(ty0[7], 1);
        #pragma unroll
        for (int m = 0; m < 8; ++m) {
            int j = j0 + m;
            if (j >= 1 && j <= S-2) {
                float tw = (m > 0) ? ty0[m-1] : tyW;
                r[m] = (tx0[m] - txm[m]) * kINVH + (ty0[m] - tw) * kINVH;
            }
            p[m] = r[m];
        }
    }
    lds_pub(srow[w], lane, p);
    if (pubEdge) coh_st_row(pubRow, lane, p);
    ++ph; gbar(ctr, ph << 5);             // A0: p0 visible batch-wide

    // ---- ap0 = A(p0); dots {pap, rap=pap, apap, rr} ----
    {
        float nN[8], nS[8];
        #pragma unroll
        for (int m = 0; m < 8; ++m) { nN[m] = 0.f; nS[m] = 0.f; }
        if (rowInt) {
            if (w == 0)  coh_ld_row(haloS, lane, nS);
            else         lds_row(srow[w-1], lane, nS);
            if (w == 15) coh_ld_row(haloN, lane, nN);
            else         lds_row(srow[w+1], lane, nN);
        }
        apply_stencil2(rowInt, j0, p, nN, nS, cxN, cxS, cyE, cyW0, ap);
        double d0 = 0.0, d2 = 0.0, d3 = 0.0;
        #pragma unroll
        for (int m = 0; m < 8; ++m) {
            d0 += (double)p[m]  * (double)ap[m];
            d2 += (double)ap[m] * (double)ap[m];
            d3 += (double)r[m]  * (double)r[m];
        }
        #pragma unroll
        for (int off = 32; off > 0; off >>= 1) {
            d0 += __shfl_down(d0, off, 64);
            d2 += __shfl_down(d2, off, 64);
            d3 += __shfl_down(d3, off, 64);
        }
        if (lane == 0) { red[8+w] = d0; red[24+w] = d2; red[40+w] = d3; }
        __syncthreads();
        if (tid == 0) {
            double t0=0, t2=0, t3=0;
            #pragma unroll
            for (int q = 0; q < 16; ++q) { t0 += red[8+q]; t2 += red[24+q]; t3 += red[40+q]; }
            __hip_atomic_store(dslot+0, t0, __ATOMIC_RELAXED, __HIP_MEMORY_SCOPE_AGENT);
            __hip_atomic_store(dslot+1, t0, __ATOMIC_RELAXED, __HIP_MEMORY_SCOPE_AGENT);
            __hip_atomic_store(dslot+2, t2, __ATOMIC_RELAXED, __HIP_MEMORY_SCOPE_AGENT);
            __hip_atomic_store(dslot+3, t3, __ATOMIC_RELAXED, __HIP_MEMORY_SCOPE_AGENT);
        }
    }
    ++ph; gbar(ctr, ph << 5);             // B0: partials visible

    double rnCur = 0.0;
    for (int it = 1; it < CG_ITERS; ++it) {
        // ---- scalars: wave 0 (lanes 0..31) reduces previous round's 32 partials ----
        if (w == 0) {
            double s0 = 0.0, s1 = 0.0, s2 = 0.0, s3 = 0.0;
            if (lane < 32) {
                const double* dr = dots + ((size_t)((b << 5) | lane) << 2);
                s0 = __hip_atomic_load(dr+0, __ATOMIC_RELAXED, __HIP_MEMORY_SCOPE_AGENT);
                s1 = __hip_atomic_load(dr+1, __ATOMIC_RELAXED, __HIP_MEMORY_SCOPE_AGENT);
                s2 = __hip_atomic_load(dr+2, __ATOMIC_RELAXED, __HIP_MEMORY_SCOPE_AGENT);
                if (it == 1)
                    s3 = __hip_atomic_load(dr+3, __ATOMIC_RELAXED, __HIP_MEMORY_SCOPE_AGENT);
            }
            #pragma unroll
            for (int off = 32; off > 0; off >>= 1) {
                s0 += __shfl_down(s0, off, 64);
                s1 += __shfl_down(s1, off, 64);
                s2 += __shfl_down(s2, off, 64);
                s3 += __shfl_down(s3, off, 64);
            }
            if (lane == 0) { red[0]=s0; red[1]=s1; red[2]=s2; red[3]=s3; }
        }
        __syncthreads();
        double pap    = red[0];
        double rap    = red[1];
        double apap   = red[2];
        double rnPrev = (it == 1) ? red[3] : rnCur;
        float alphaF = (float)(rnPrev / fmax(pap, 1e-6));
        double aD = (double)alphaF;
        rnCur = rnPrev - 2.0 * aD * rap + aD * aD * apap;
        float betaF = (float)(rnCur / fmax(rnPrev, 1e-6));

        // ---- vector updates (all in registers) ----
        #pragma unroll
        for (int m = 0; m < 8; ++m) {
            x[m] += alphaF * p[m];
            r[m]  = r[m] - alphaF * ap[m];
            p[m]  = r[m] + betaF * p[m];
        }
        lds_pub(srow[w], lane, p);        // srow reads of prev round done pre-gbar B
        if (pubEdge) coh_st_row(pubRow, lane, p);
        ++ph; gbar(ctr, ph << 5);         // A: new p visible

        // ---- ap = A(p); dots {pap, rap, apap} ----
        float nN[8], nS[8];
        #pragma unroll
        for (int m = 0; m < 8; ++m) { nN[m] = 0.f; nS[m] = 0.f; }
        if (rowInt) {
            if (w == 0)  coh_ld_row(haloS, lane, nS);
            else         lds_row(srow[w-1], lane, nS);
            if (w == 15) coh_ld_row(haloN, lane, nN);
            else         lds_row(srow[w+1], lane, nN);
        }
        apply_stencil2(rowInt, j0, p, nN, nS, cxN, cxS, cyE, cyW0, ap);
        double d0 = 0.0, d1 = 0.0, d2 = 0.0;
        #pragma unroll
        for (int m = 0; m < 8; ++m) {
            d0 += (double)p[m]  * (double)ap[m];
            d1 += (double)r[m]  * (double)ap[m];
            d2 += (double)ap[m] * (double)ap[m];
        }
        #pragma unroll
        for (int off = 32; off > 0; off >>= 1) {
            d0 += __shfl_down(d0, off, 64);
            d1 += __shfl_down(d1, off, 64);
            d2 += __shfl_down(d2, off, 64);
        }
        if (lane == 0) { red[8+w] = d0; red[24+w] = d1; red[40+w] = d2; }
        __syncthreads();
        if (tid == 0) {
            double t0=0, t1=0, t2=0;
            #pragma unroll
            for (int q = 0; q < 16; ++q) { t0 += red[8+q]; t1 += red[24+q]; t2 += red[40+q]; }
            __hip_atomic_store(dslot+0, t0, __ATOMIC_RELAXED, __HIP_MEMORY_SCOPE_AGENT);
            __hip_atomic_store(dslot+1, t1, __ATOMIC_RELAXED, __HIP_MEMORY_SCOPE_AGENT);
            __hip_atomic_store(dslot+2, t2, __ATOMIC_RELAXED, __HIP_MEMORY_SCOPE_AGENT);
        }
        ++ph; gbar(ctr, ph << 5);         // B: partials visible
    }

    // ---- finale: alpha_19 = rn_19 / pap_19; out = zb(u + x + alpha*p) ----
    {
        if (w == 0) {
            double s0 = 0.0;
            if (lane < 32) {
                const double* dr = dots + ((size_t)((b << 5) | lane) << 2);
                s0 = __hip_atomic_load(dr+0, __ATOMIC_RELAXED, __HIP_MEMORY_SCOPE_AGENT);
            }
            #pragma unroll
            for (int off = 32; off > 0; off >>= 1) s0 += __shfl_down(s0, off, 64);
            if (lane == 0) red[0] = s0;
        }
        __syncthreads();
        double pap = red[0];
        float alphaF = (float)(rnCur / fmax(pap, 1e-6));
        float o[8];
        #pragma unroll
        for (int m = 0; m < 8; ++m) o[m] = 0.f;
        if (rowInt) {
            float uu[8];
            load8(u + base, uu);
            #pragma unroll
            for (int m = 0; m < 8; ++m) {
                int j = j0 + m;
                if (j >= 1 && j <= S-2) o[m] = uu[m] + x[m] + alphaF * p[m];
            }
        }
        store8(out + base, o);
    }
}

extern "C" void kernel_launch(void* const* d_in, const int* in_sizes, int n_in,
                              void* d_out, int out_size, void* d_ws, size_t ws_size,
                              hipStream_t stream) {
    const float* coeff = (const float*)d_in[0];
    const float* u     = (const float*)d_in[1];
    const float* beta  = (const float*)d_in[2];
    float* out = (float*)d_out;

    float* ws    = (float*)d_ws;
    float* tauxB = ws;                    // NTOT (b-stride NFACE inside)
    float* tauyB = ws + (size_t)NTOT;
    float* cxB   = ws + 2*(size_t)NTOT;
    float* cyB   = ws + 3*(size_t)NTOT;
    float* prow  = ws + 4*(size_t)NTOT;   // [256 blocks][2 edges][512] floats
    double* dots = (double*)(prow + (size_t)NBLK4*2*512);   // [8][32][4] doubles
    unsigned* bar = (unsigned*)(dots + 8*32*4);             // 8 padded counters

    // barrier counters must start at 0 (monotonic within one launch)
    (void)hipMemsetAsync(bar, 0, 4096, stream);

    k_setup<<<8192, dim3(256), 0, stream>>>(coeff, u, beta, tauxB, tauyB, cxB, cyB);
    k_cg<<<NBLK4, dim3(1024), 0, stream>>>(tauxB, tauyB, cxB, cyB, u, out,
                                           prow, dots, bar);
}